// Round 4
// baseline (188.970 us; speedup 1.0000x reference)
//
#include <hip/hip_runtime.h>
#include <hip/hip_bf16.h>
#include <math.h>

#define NTOT 2048   // N*T
#define DIM  128    // D == E1
#define MSPLIT 32   // split-K for gk_mlp1t (4 tiles x 32 splits x 4 k = 512 blocks)
#define ZSPLIT 16   // split-K for xz stage (128 jobs at 64x64 tiles)
#define JT 16       // jsd tile width (columns)
#define JNC 128     // jsd n-chunk in LDS
#define JNSPLIT 16  // jsd n splits (36*16 = 576 jobs, single chunk each)

struct P4 { const float* p[4]; };

// ---------------------------------------------------------------- H pipeline
// Gs[k][split] = partial X_k^T @ W1_k  (no atomics; consumer sums splits)
// 64x64 tile, 4x4 micro-tile (1 FLOP/LDS-byte, 2x the 2x2 version), K=64/block.
// grid (4 tiles, MSPLIT, 4 k) = 512 blocks, block 256. Register double-buffered.
__global__ __launch_bounds__(256) void gk_mlp1t(P4 X, P4 W1, float* __restrict__ Gs) {
  int k = blockIdx.z;
  int m0 = (blockIdx.x & 1) * 64;
  int e0 = (blockIdx.x >> 1) * 64;
  int split = blockIdx.y;
  int n0 = split * (NTOT / MSPLIT);
  const float* Xp = X.p[k];
  const float* Wp = W1.p[k];
  __shared__ float Xs[32][68], Ws[32][68];   // 68: float4-aligned pad
  int tid = threadIdx.x;
  int lr = tid >> 4;              // load rows lr, lr+16
  int lc = (tid & 15) * 4;
  int tx = tid & 15, ty = tid >> 4;
  float4 acc0 = make_float4(0,0,0,0), acc1 = acc0, acc2 = acc0, acc3 = acc0;
  long g0 = (long)(n0 + lr) * DIM;
  float4 px0 = *(const float4*)(Xp + g0 + m0 + lc);
  float4 px1 = *(const float4*)(Xp + g0 + 16 * DIM + m0 + lc);
  float4 pw0 = *(const float4*)(Wp + g0 + e0 + lc);
  float4 pw1 = *(const float4*)(Wp + g0 + 16 * DIM + e0 + lc);
  for (int nb = 0; nb < NTOT / MSPLIT; nb += 32) {
    *(float4*)&Xs[lr][lc]      = px0;
    *(float4*)&Xs[lr + 16][lc] = px1;
    *(float4*)&Ws[lr][lc]      = pw0;
    *(float4*)&Ws[lr + 16][lc] = pw1;
    __syncthreads();
    if (nb + 32 < NTOT / MSPLIT) {
      long gn = (long)(n0 + nb + 32 + lr) * DIM;
      px0 = *(const float4*)(Xp + gn + m0 + lc);
      px1 = *(const float4*)(Xp + gn + 16 * DIM + m0 + lc);
      pw0 = *(const float4*)(Wp + gn + e0 + lc);
      pw1 = *(const float4*)(Wp + gn + 16 * DIM + e0 + lc);
    }
    #pragma unroll
    for (int nn = 0; nn < 32; ++nn) {
      float4 a = *(const float4*)&Xs[nn][4 * ty];   // m-frag (broadcast/16 lanes)
      float4 b = *(const float4*)&Ws[nn][4 * tx];   // e-frag (2-way, free)
      acc0.x += a.x*b.x; acc0.y += a.x*b.y; acc0.z += a.x*b.z; acc0.w += a.x*b.w;
      acc1.x += a.y*b.x; acc1.y += a.y*b.y; acc1.z += a.y*b.z; acc1.w += a.y*b.w;
      acc2.x += a.z*b.x; acc2.y += a.z*b.y; acc2.z += a.z*b.z; acc2.w += a.z*b.w;
      acc3.x += a.w*b.x; acc3.y += a.w*b.y; acc3.z += a.w*b.z; acc3.w += a.w*b.w;
    }
    __syncthreads();
  }
  float* Gk = Gs + ((long)k * MSPLIT + split) * 16384;
  int m = m0 + 4 * ty, e = e0 + 4 * tx;
  *(float4*)(Gk + (m + 0) * DIM + e) = acc0;
  *(float4*)(Gk + (m + 1) * DIM + e) = acc1;
  *(float4*)(Gk + (m + 2) * DIM + e) = acc2;
  *(float4*)(Gk + (m + 3) * DIM + e) = acc3;
}

// Fused gk_mlp2 + gk_ab (one launch, no Mk round-trip). grid 128, block 256
__global__ __launch_bounds__(256) void gk_mab(const float* __restrict__ Gs, P4 B1, P4 W2, P4 B2,
                                              const float* __restrict__ fW1, float* __restrict__ AB) {
  int m = blockIdx.x;
  int e = threadIdx.x & 127;
  int half = threadIdx.x >> 7;      // 0,1
  int k0 = half, k1 = half + 2;
  __shared__ float rk[4][DIM];      // relu(sum_s Gs + b1)
  __shared__ float mk[4][DIM];      // M rows
  {
    const float* G0 = Gs + (long)k0 * MSPLIT * 16384 + m * DIM + e;
    const float* G1 = Gs + (long)k1 * MSPLIT * 16384 + m * DIM + e;
    float s0 = 0.f, s1 = 0.f;
    #pragma unroll
    for (int s = 0; s < MSPLIT; ++s) { s0 += G0[s * 16384]; s1 += G1[s * 16384]; }
    rk[k0][e] = fmaxf(s0 + B1.p[k0][e], 0.f);
    rk[k1][e] = fmaxf(s1 + B1.p[k1][e], 0.f);
  }
  __syncthreads();
  {
    const float* Wa = W2.p[k0];
    const float* Wb = W2.p[k1];
    float a0 = B2.p[k0][e], a1 = B2.p[k1][e];
    #pragma unroll 8
    for (int j = 0; j < DIM; ++j) {
      a0 += rk[k0][j] * Wa[j * DIM + e];
      a1 += rk[k1][j] * Wb[j * DIM + e];
    }
    mk[k0][e] = a0;
    mk[k1][e] = a1;
  }
  __syncthreads();
  const float* Ma = mk[half];           // h=0: it ; h=1: inw
  const float* Mb = mk[half + 2];       // h=0: t2n; h=1: n2t
  const float* W0 = fW1 + (half == 0 ? 0 : 128) * DIM;
  const float* W1p = fW1 + (half == 0 ? 256 : 384) * DIM;
  float acc = 0.f;
  #pragma unroll 8
  for (int j = 0; j < DIM; ++j)
    acc += Ma[j] * W0[j * DIM + e] + Mb[j] * W1p[j * DIM + e];
  AB[(long)half * 16384 + m * DIM + e] = acc;
}

// Fused H1+H2, 4 rows per block (512 blocks = 2/CU for L2-latency hiding),
// transposed output HrawT[e][n]. Body proven in round-2 mega stage 3.
__global__ __launch_bounds__(256) void gk_h12t(const float* __restrict__ xt, const float* __restrict__ xn,
                                               const float* __restrict__ AB, const float* __restrict__ fb1,
                                               const float* __restrict__ fW2, const float* __restrict__ fb2,
                                               float* __restrict__ HrawT) {
  int n0 = blockIdx.x * 4;                 // 512 blocks
  int e  = threadIdx.x & 127;
  int half = threadIdx.x >> 7;             // row-pair selector (0/1)
  __shared__ float xT[DIM][4], nT[DIM][4], h1T[DIM][4];
  {
    int c = threadIdx.x & 31, rq = threadIdx.x >> 5;   // rq<4: xt ; rq>=4: xn
    const float* src = (rq < 4) ? (xt + (long)(n0 + rq) * DIM)
                                : (xn + (long)(n0 + rq - 4) * DIM);
    float (*dst)[4] = (rq < 4) ? xT : nT;
    int rr = rq & 3;
    #pragma unroll
    for (int i = 0; i < 4; ++i) {
      int d = c + 32 * i;
      dst[d][rr] = src[d];
    }
  }
  __syncthreads();
  float2 acc1 = make_float2(0.f, 0.f);     // rows n0+half*2, +1
  #pragma unroll 8
  for (int k = 0; k < DIM; ++k) {
    float a = AB[k * DIM + e];
    float b = AB[16384 + k * DIM + e];
    float2 xv = *(const float2*)&xT[k][half * 2];
    float2 nv = *(const float2*)&nT[k][half * 2];
    acc1.x += xv.x * a + nv.x * b;
    acc1.y += xv.y * a + nv.y * b;
  }
  float b1v = fb1[e];
  float2 h1 = make_float2(fmaxf(acc1.x + b1v, 0.f), fmaxf(acc1.y + b1v, 0.f));
  *(float2*)&h1T[e][half * 2] = h1;
  __syncthreads();
  float2 acc2 = make_float2(0.f, 0.f);
  #pragma unroll 8
  for (int j = 0; j < DIM; ++j) {
    float wv = fW2[j * DIM + e];
    float2 hv = *(const float2*)&h1T[j][half * 2];
    acc2.x += hv.x * wv;
    acc2.y += hv.y * wv;
  }
  float b2v = fb2[e];
  float2 o = make_float2(acc2.x + b2v, acc2.y + b2v);
  *(float2*)&HrawT[(long)e * NTOT + n0 + half * 2] = o;
}

// ---------------------------------------------------------------- reductions
// fused colstats+softmax (one block/column, column register-resident).
// Block 0 also zeroes Gacc (jsd runs strictly after this kernel).
__global__ __launch_bounds__(256) void colsoft_k(const float* __restrict__ HrawT,
                                                 float* __restrict__ HTp, float* __restrict__ Ecol,
                                                 float* __restrict__ Gacc) {
  int e = blockIdx.x;
  int t = threadIdx.x;
  if (e == 0 && t < DIM) Gacc[t] = 0.f;
  __shared__ float sa[4], sb[4], sc[4];
  float v[8];
  float sum = 0.f, sq = 0.f, mx = -3.4e38f;
  #pragma unroll
  for (int r = 0; r < 8; ++r) {
    float x = HrawT[(long)e * NTOT + t + 256 * r];   // coalesced
    v[r] = x;
    sum += x; sq += x * x; mx = fmaxf(mx, x);
  }
  #pragma unroll
  for (int o = 32; o > 0; o >>= 1) {
    sum += __shfl_down(sum, o);
    sq  += __shfl_down(sq, o);
    mx   = fmaxf(mx, __shfl_down(mx, o));
  }
  if ((t & 63) == 0) { int w = t >> 6; sa[w] = sum; sb[w] = sq; sc[w] = mx; }
  __syncthreads();
  sum = sa[0] + sa[1] + sa[2] + sa[3];
  sq  = sb[0] + sb[1] + sb[2] + sb[3];
  mx  = fmaxf(fmaxf(sc[0], sc[1]), fmaxf(sc[2], sc[3]));
  float mean = sum * (1.f / NTOT);
  float var  = (sq - sum * mean) * (1.f / (NTOT - 1));
  float ia   = 1.f / (sqrtf(fmaxf(var, 0.f)) + 1e-6f);
  float smax = (mx - mean) * ia;
  __syncthreads();

  float den = 0.f;
  #pragma unroll
  for (int r = 0; r < 8; ++r) {
    float s = (v[r] - mean) * ia - smax;
    v[r] = s;
    den += __expf(s);
  }
  #pragma unroll
  for (int o = 32; o > 0; o >>= 1) den += __shfl_down(den, o);
  if ((t & 63) == 0) sa[t >> 6] = den;
  __syncthreads();
  den = sa[0] + sa[1] + sa[2] + sa[3];
  float logden = __logf(den);
  float invden = 1.f / den;
  __syncthreads();

  float ent = 0.f;
  #pragma unroll
  for (int r = 0; r < 8; ++r) {
    float s = v[r];
    float pv = __expf(s) * invden;
    HTp[(long)e * NTOT + t + 256 * r] = pv;
    ent += pv * (s - logden);
  }
  #pragma unroll
  for (int o = 32; o > 0; o >>= 1) ent += __shfl_down(ent, o);
  if ((t & 63) == 0) sa[t >> 6] = ent;
  __syncthreads();
  if (t == 0) Ecol[e] = sa[0] + sa[1] + sa[2] + sa[3];
}

// ---------------------------------------------------------------- jsd + xz (fused launch)
// bid < 576: pairwise-JSD log part (36 tile-pairs x 16 n-splits)
// bid >= 576: Xzs partial H^T x, 64x64 tiles, 4x4 micro (128 jobs)
__global__ __launch_bounds__(256) void jx_k(const float* __restrict__ HTp,
                                            const float* __restrict__ xt, const float* __restrict__ xn,
                                            float* __restrict__ g, float* __restrict__ Xzs) {
  __shared__ union {
    struct { float Ti[JT][JNC + 2], Tj[JT][JNC + 2], red[JT][JT + 1]; } j;   // 17.7 KB
    struct { float As[32][68], Bs[32][68]; } x;                              // 17.4 KB
  } sm;
  int bid = blockIdx.x;
  int tid = threadIdx.x;

  if (bid < 576) {
    // ---- jsd: single JNC-wide chunk per job
    int ny = bid / 36, b = bid - ny * 36;
    int bi = 0, rem = b;
    while (rem >= 8 - bi) { rem -= 8 - bi; ++bi; }
    int bj = bi + rem;                      // bi <= bj
    int n0 = ny * (NTOT / JNSPLIT);         // == ny * JNC
    int ti = tid >> 4, tj = tid & 15;
    bool active = (bi != bj) || (ti < tj);
    int lc = tid >> 4, ln = (tid & 15) * 8;
    const float* si = HTp + (long)(bi * JT + lc) * NTOT + n0 + ln;
    const float* sj = HTp + (long)(bj * JT + lc) * NTOT + n0 + ln;
    #pragma unroll
    for (int r = 0; r < 8; ++r) sm.j.Ti[lc][ln + r] = si[r];
    #pragma unroll
    for (int r = 0; r < 8; ++r) sm.j.Tj[lc][ln + r] = sj[r];
    __syncthreads();
    float acc = 0.f;
    if (active) {
      #pragma unroll 4
      for (int n = 0; n < JNC; ++n) {
        float s = sm.j.Ti[ti][n] + sm.j.Tj[tj][n];
        acc += s * __logf(fmaxf(0.5f * s, 1e-38f));
      }
    }
    sm.j.red[ti][tj] = active ? acc : 0.f;
    __syncthreads();
    if (tid < JT) {
      float s = 0.f;
      #pragma unroll
      for (int q = 0; q < JT; ++q) s += sm.j.red[tid][q];
      atomicAdd(&g[bi * JT + tid], -s);
    } else if (tid < 2 * JT) {
      int c2 = tid - JT;
      float s = 0.f;
      #pragma unroll
      for (int i = 0; i < JT; ++i) s += sm.j.red[i][c2];
      atomicAdd(&g[bj * JT + c2], -s);
    }
  } else {
    // ---- xz: Xzs[bt][split][e][d] = partial sum_n Hsoft[n,e] x[n][d]
    int id = bid - 576;                    // 0..127
    int bt = id >> 6;
    int split = (id >> 2) & 15;
    int t4 = id & 3;
    int e0 = (t4 & 1) * 64, d0 = (t4 >> 1) * 64;
    int n0 = split * (NTOT / ZSPLIT);      // 128-wide slice
    const float* x = bt ? xn : xt;
    float* C = Xzs + ((long)bt * ZSPLIT + split) * 16384;
    int col = tid & 31, er = tid >> 5;     // As staging: e rows er+8r, n col
    int lr = tid >> 4, lc = (tid & 15) * 4;
    int tx = tid & 15, ty = tid >> 4;
    float4 acc0 = make_float4(0,0,0,0), acc1 = acc0, acc2 = acc0, acc3 = acc0;
    float pa[8]; float4 pb0, pb1;
    #pragma unroll
    for (int r = 0; r < 8; ++r) pa[r] = HTp[(long)(e0 + er + 8 * r) * NTOT + n0 + col];
    pb0 = *(const float4*)(x + (long)(n0 + lr) * DIM + d0 + lc);
    pb1 = *(const float4*)(x + (long)(n0 + lr + 16) * DIM + d0 + lc);
    for (int nb = 0; nb < NTOT / ZSPLIT; nb += 32) {
      #pragma unroll
      for (int r = 0; r < 8; ++r) sm.x.As[col][er + 8 * r] = pa[r];
      *(float4*)&sm.x.Bs[lr][lc]      = pb0;
      *(float4*)&sm.x.Bs[lr + 16][lc] = pb1;
      __syncthreads();
      if (nb + 32 < NTOT / ZSPLIT) {
        #pragma unroll
        for (int r = 0; r < 8; ++r)
          pa[r] = HTp[(long)(e0 + er + 8 * r) * NTOT + n0 + nb + 32 + col];
        pb0 = *(const float4*)(x + (long)(n0 + nb + 32 + lr) * DIM + d0 + lc);
        pb1 = *(const float4*)(x + (long)(n0 + nb + 48 + lr) * DIM + d0 + lc);
      }
      #pragma unroll
      for (int nn = 0; nn < 32; ++nn) {
        float4 a = *(const float4*)&sm.x.As[nn][4 * ty];   // e-frag
        float4 b = *(const float4*)&sm.x.Bs[nn][4 * tx];   // d-frag
        acc0.x += a.x*b.x; acc0.y += a.x*b.y; acc0.z += a.x*b.z; acc0.w += a.x*b.w;
        acc1.x += a.y*b.x; acc1.y += a.y*b.y; acc1.z += a.y*b.z; acc1.w += a.y*b.w;
        acc2.x += a.z*b.x; acc2.y += a.z*b.y; acc2.z += a.z*b.z; acc2.w += a.z*b.w;
        acc3.x += a.w*b.x; acc3.y += a.w*b.y; acc3.z += a.w*b.z; acc3.w += a.w*b.w;
      }
      __syncthreads();
    }
    int e = e0 + 4 * ty, d = d0 + 4 * tx;
    *(float4*)(C + (e + 0) * DIM + d) = acc0;
    *(float4*)(C + (e + 1) * DIM + d) = acc1;
    *(float4*)(C + (e + 2) * DIM + d) = acc2;
    *(float4*)(C + (e + 3) * DIM + d) = acc3;
  }
}

// Zw[bt][e][d] = w[e] * sum_k (sum_s Xzs[bt][s][e][k]) * theta[k][d]
// w computed per-wave via 64-lane butterfly (no LDS/syncs; proven round 2).
// grid (128, 2), block 128.
__global__ __launch_bounds__(128) void zs_k(const float* __restrict__ Xzs, const float* __restrict__ thT,
                                            const float* __restrict__ thN, const float* __restrict__ g,
                                            const float* __restrict__ Ecol, float* __restrict__ Zw) {
  int e = blockIdx.x, d = threadIdx.x, bt = blockIdx.y;
  float we;
  {
    int l = threadIdx.x & 63;
    float gA = g[l], gB = g[l + 64];
    float eA = Ecol[l], eB = Ecol[l + 64];
    float S = eA + eB;
    #pragma unroll
    for (int o = 32; o > 0; o >>= 1) S += __shfl_xor(S, o);
    float jA = (gA + 126.f * eA + S) * (1.f / 256.f);
    float jB = (gB + 126.f * eB + S) * (1.f / 256.f);
    float sn = jA + jB;
    #pragma unroll
    for (int o = 32; o > 0; o >>= 1) sn += __shfl_xor(sn, o);
    float mean = sn * (1.f / 128.f);
    float dA = jA - mean, dB = jB - mean;
    float q = dA * dA + dB * dB;
    #pragma unroll
    for (int o = 32; o > 0; o >>= 1) q += __shfl_xor(q, o);
    float inv = 1.f / (sqrtf(q * (1.f / 127.f)) + 1e-6f);
    float nA = dA * inv, nB = dB * inv;
    float mx = fmaxf(nA, nB);
    #pragma unroll
    for (int o = 32; o > 0; o >>= 1) mx = fmaxf(mx, __shfl_xor(mx, o));
    float xA = __expf(nA - mx), xB = __expf(nB - mx);
    float den = xA + xB;
    #pragma unroll
    for (int o = 32; o > 0; o >>= 1) den += __shfl_xor(den, o);
    float sel = (e < 64) ? nA : nB;
    float ne = __shfl(sel, e & 63);
    we = __expf(ne - mx) / den;
  }
  const float* src = Xzs + (long)bt * ZSPLIT * 16384 + e * DIM + d;
  const float* th = bt ? thN : thT;
  __shared__ float s[DIM];
  float xv = 0.f;
  #pragma unroll
  for (int sp = 0; sp < ZSPLIT; ++sp) xv += src[sp * 16384];
  s[d] = xv;
  __syncthreads();
  float acc = 0.f;
  #pragma unroll 8
  for (int k = 0; k < DIM; ++k) acc += s[k] * th[(long)k * DIM + d];
  Zw[bt * 16384 + e * DIM + d] = acc * we;
}

// out[n][d] = x[n][d] + elu( sum_e Hsoft[n,e] Zw[e][d] )  (H read from HTp)
// grid (4, 64, 2), block 256. Register double-buffered staging.
__global__ __launch_bounds__(256) void uk_t(const float* __restrict__ HTp, const float* __restrict__ Zw,
                                            const float* __restrict__ xt, const float* __restrict__ xn,
                                            float* __restrict__ out) {
  int bt = blockIdx.z;
  const float* x = bt ? xn : xt;
  const float* B = Zw + bt * 16384;
  float* o = out + (long)bt * NTOT * DIM;
  int d0 = blockIdx.x * 32, n0 = blockIdx.y * 32;
  __shared__ float As[32][33], Bs[32][36];   // As[n][e], Bs[e][d]
  int tid = threadIdx.x, col = tid & 31, row = tid >> 5;
  int lr = tid >> 3, lc4 = (tid & 7) * 4;
  int tx = tid & 15, ty = tid >> 4;
  float a00 = 0.f, a01 = 0.f, a10 = 0.f, a11 = 0.f;
  float pa[4]; float4 pb;
  #pragma unroll
  for (int r = 0; r < 4; ++r) pa[r] = HTp[(long)(row + r * 8) * NTOT + n0 + col];
  pb = *(const float4*)(B + (long)lr * DIM + d0 + lc4);
  for (int eb = 0; eb < DIM; eb += 32) {
    #pragma unroll
    for (int r = 0; r < 4; ++r) As[col][row + r * 8] = pa[r];
    *(float4*)&Bs[lr][lc4] = pb;
    __syncthreads();
    if (eb + 32 < DIM) {
      #pragma unroll
      for (int r = 0; r < 4; ++r)
        pa[r] = HTp[(long)(eb + 32 + row + r * 8) * NTOT + n0 + col];
      pb = *(const float4*)(B + (long)(eb + 32 + lr) * DIM + d0 + lc4);
    }
    #pragma unroll
    for (int ee = 0; ee < 32; ++ee) {
      float x0 = As[2*ty][ee], x1 = As[2*ty+1][ee];
      float b0 = Bs[ee][2*tx], b1 = Bs[ee][2*tx+1];
      a00 += x0 * b0; a01 += x0 * b1;
      a10 += x1 * b0; a11 += x1 * b1;
    }
    __syncthreads();
  }
  int n = n0 + 2 * ty, d = d0 + 2 * tx;
  long i0 = (long)n * DIM + d, i1 = i0 + DIM;
  float e00 = a00 > 0.f ? a00 : expm1f(a00);
  float e01 = a01 > 0.f ? a01 : expm1f(a01);
  float e10 = a10 > 0.f ? a10 : expm1f(a10);
  float e11 = a11 > 0.f ? a11 : expm1f(a11);
  o[i0]     = x[i0]     + e00;
  o[i0 + 1] = x[i0 + 1] + e01;
  o[i1]     = x[i1]     + e10;
  o[i1 + 1] = x[i1 + 1] + e11;
}

// ---------------------------------------------------------------- launcher
extern "C" void kernel_launch(void* const* d_in, const int* in_sizes, int n_in,
                              void* d_out, int out_size, void* d_ws, size_t ws_size,
                              hipStream_t stream) {
  const float* xt = (const float*)d_in[0];   // x_time (f32)
  const float* xn = (const float*)d_in[1];   // x_news
  const float *W1[4], *b1[4], *W2[4], *b2[4];
  for (int k = 0; k < 4; ++k) {           // it, inw, t2n, n2t
    W1[k] = (const float*)d_in[2 + 4*k];
    b1[k] = (const float*)d_in[3 + 4*k];
    W2[k] = (const float*)d_in[4 + 4*k];
    b2[k] = (const float*)d_in[5 + 4*k];
  }
  const float* fW1 = (const float*)d_in[18];
  const float* fb1 = (const float*)d_in[19];
  const float* fW2 = (const float*)d_in[20];
  const float* fb2 = (const float*)d_in[21];
  const float* thT = (const float*)d_in[22];
  const float* thN = (const float*)d_in[23];

  // ws map (floats), peak 3211648 = 12.8 MB (no host-side zeroing needed)
  float* ws    = (float*)d_ws;
  float* Gacc  = ws;                         // [0,128)  zeroed by colsoft block 0
  float* Ecol  = ws + 128;                   // [128,256)
  float* Zw    = ws + 384;                   // [384,33152)
  float* Xzs   = ws + 33152;                 // 2*ZSPLIT*16384 = 524288 -> 557440
  float* Gs    = ws + 557440;                // 4*MSPLIT*16384 = 2097152 -> 2654592
  float* AB    = ws + 2654592;               // 32768 -> 2687360
  float* HrawT = ws + 2687360;               // 262144 -> 2949504 (transposed [e][n])
  float* HTp   = ws + 2949504;               // 262144 -> 3211648

  float* out = (float*)d_out;                // f32 output, [time | news]

  P4 Xs  = {{xt, xn, xn, xt}};
  P4 W1s = {{W1[0], W1[1], W1[2], W1[3]}};
  P4 B1s = {{b1[0], b1[1], b1[2], b1[3]}};
  P4 W2s = {{W2[0], W2[1], W2[2], W2[3]}};
  P4 B2s = {{b2[0], b2[1], b2[2], b2[3]}};

  gk_mlp1t<<<dim3(4, MSPLIT, 4), 256, 0, stream>>>(Xs, W1s, Gs);
  gk_mab  <<<128, 256, 0, stream>>>(Gs, B1s, W2s, B2s, fW1, AB);
  gk_h12t <<<512, 256, 0, stream>>>(xt, xn, AB, fb1, fW2, fb2, HrawT);

  colsoft_k<<<DIM, 256, 0, stream>>>(HrawT, HTp, Ecol, Gacc);

  jx_k<<<576 + 128, 256, 0, stream>>>(HTp, xt, xn, Gacc, Xzs);

  zs_k<<<dim3(128, 2), 128, 0, stream>>>(Xzs, thT, thN, Gacc, Ecol, Zw);
  uk_t<<<dim3(4, 64, 2), 256, 0, stream>>>(HTp, Zw, xt, xn, out);

  (void)in_sizes; (void)n_in; (void)out_size; (void)ws_size;
}

// Round 5
// 187.775 us; speedup vs baseline: 1.0064x; 1.0064x over previous
//
#include <hip/hip_runtime.h>
#include <hip/hip_bf16.h>
#include <math.h>

#define NTOT 2048   // N*T
#define DIM  128    // D == E1
#define MSPLIT 32   // split-K for gk_mlp1t (4 tiles x 32 splits x 4 k = 512 blocks)
#define ZSPLIT 16   // split-K for xz stage (512 jobs at 32x32 tiles, R3-proven)
#define JT 16       // jsd tile width (columns)
#define JNC 128     // jsd n-chunk in LDS
#define JNSPLIT 16  // jsd n splits (36*16 = 576 jobs, single chunk each)

struct P4 { const float* p[4]; };

// ---------------------------------------------------------------- H pipeline
// Gs[k][split] = partial X_k^T @ W1_k  (no atomics; consumer sums splits)
// 64x64 tile, 4x4 micro-tile (1 FLOP/LDS-byte), K=64/block. R4-proven numerics.
// grid (4 tiles, MSPLIT, 4 k) = 512 blocks (2/CU), block 256.
__global__ __launch_bounds__(256) void gk_mlp1t(P4 X, P4 W1, float* __restrict__ Gs) {
  int k = blockIdx.z;
  int m0 = (blockIdx.x & 1) * 64;
  int e0 = (blockIdx.x >> 1) * 64;
  int split = blockIdx.y;
  int n0 = split * (NTOT / MSPLIT);
  const float* Xp = X.p[k];
  const float* Wp = W1.p[k];
  __shared__ float Xs[32][68], Ws[32][68];   // 68: float4-aligned pad
  int tid = threadIdx.x;
  int lr = tid >> 4;              // load rows lr, lr+16
  int lc = (tid & 15) * 4;
  int tx = tid & 15, ty = tid >> 4;
  float4 acc0 = make_float4(0,0,0,0), acc1 = acc0, acc2 = acc0, acc3 = acc0;
  long g0 = (long)(n0 + lr) * DIM;
  float4 px0 = *(const float4*)(Xp + g0 + m0 + lc);
  float4 px1 = *(const float4*)(Xp + g0 + 16 * DIM + m0 + lc);
  float4 pw0 = *(const float4*)(Wp + g0 + e0 + lc);
  float4 pw1 = *(const float4*)(Wp + g0 + 16 * DIM + e0 + lc);
  for (int nb = 0; nb < NTOT / MSPLIT; nb += 32) {
    *(float4*)&Xs[lr][lc]      = px0;
    *(float4*)&Xs[lr + 16][lc] = px1;
    *(float4*)&Ws[lr][lc]      = pw0;
    *(float4*)&Ws[lr + 16][lc] = pw1;
    __syncthreads();
    if (nb + 32 < NTOT / MSPLIT) {
      long gn = (long)(n0 + nb + 32 + lr) * DIM;
      px0 = *(const float4*)(Xp + gn + m0 + lc);
      px1 = *(const float4*)(Xp + gn + 16 * DIM + m0 + lc);
      pw0 = *(const float4*)(Wp + gn + e0 + lc);
      pw1 = *(const float4*)(Wp + gn + 16 * DIM + e0 + lc);
    }
    #pragma unroll
    for (int nn = 0; nn < 32; ++nn) {
      float4 a = *(const float4*)&Xs[nn][4 * ty];   // m-frag
      float4 b = *(const float4*)&Ws[nn][4 * tx];   // e-frag
      acc0.x += a.x*b.x; acc0.y += a.x*b.y; acc0.z += a.x*b.z; acc0.w += a.x*b.w;
      acc1.x += a.y*b.x; acc1.y += a.y*b.y; acc1.z += a.y*b.z; acc1.w += a.y*b.w;
      acc2.x += a.z*b.x; acc2.y += a.z*b.y; acc2.z += a.z*b.z; acc2.w += a.z*b.w;
      acc3.x += a.w*b.x; acc3.y += a.w*b.y; acc3.z += a.w*b.z; acc3.w += a.w*b.w;
    }
    __syncthreads();
  }
  float* Gk = Gs + ((long)k * MSPLIT + split) * 16384;
  int m = m0 + 4 * ty, e = e0 + 4 * tx;
  *(float4*)(Gk + (m + 0) * DIM + e) = acc0;
  *(float4*)(Gk + (m + 1) * DIM + e) = acc1;
  *(float4*)(Gk + (m + 2) * DIM + e) = acc2;
  *(float4*)(Gk + (m + 3) * DIM + e) = acc3;
}

// Fused gk_mlp2 + gk_ab (one launch, no Mk round-trip). grid 128, block 256
__global__ __launch_bounds__(256) void gk_mab(const float* __restrict__ Gs, P4 B1, P4 W2, P4 B2,
                                              const float* __restrict__ fW1, float* __restrict__ AB) {
  int m = blockIdx.x;
  int e = threadIdx.x & 127;
  int half = threadIdx.x >> 7;      // 0,1
  int k0 = half, k1 = half + 2;
  __shared__ float rk[4][DIM];      // relu(sum_s Gs + b1)
  __shared__ float mk[4][DIM];      // M rows
  {
    const float* G0 = Gs + (long)k0 * MSPLIT * 16384 + m * DIM + e;
    const float* G1 = Gs + (long)k1 * MSPLIT * 16384 + m * DIM + e;
    float s0 = 0.f, s1 = 0.f;
    #pragma unroll
    for (int s = 0; s < MSPLIT; ++s) { s0 += G0[s * 16384]; s1 += G1[s * 16384]; }
    rk[k0][e] = fmaxf(s0 + B1.p[k0][e], 0.f);
    rk[k1][e] = fmaxf(s1 + B1.p[k1][e], 0.f);
  }
  __syncthreads();
  {
    const float* Wa = W2.p[k0];
    const float* Wb = W2.p[k1];
    float a0 = B2.p[k0][e], a1 = B2.p[k1][e];
    #pragma unroll 8
    for (int j = 0; j < DIM; ++j) {
      a0 += rk[k0][j] * Wa[j * DIM + e];
      a1 += rk[k1][j] * Wb[j * DIM + e];
    }
    mk[k0][e] = a0;
    mk[k1][e] = a1;
  }
  __syncthreads();
  const float* Ma = mk[half];           // h=0: it ; h=1: inw
  const float* Mb = mk[half + 2];       // h=0: t2n; h=1: n2t
  const float* W0 = fW1 + (half == 0 ? 0 : 128) * DIM;
  const float* W1p = fW1 + (half == 0 ? 256 : 384) * DIM;
  float acc = 0.f;
  #pragma unroll 8
  for (int j = 0; j < DIM; ++j)
    acc += Ma[j] * W0[j * DIM + e] + Mb[j] * W1p[j * DIM + e];
  AB[(long)half * 16384 + m * DIM + e] = acc;
}

// Fused H1+H2, 8 rows per block, 512 threads (grid 256 -> 8 waves/block =
// 2 waves/SIMD, double the latency hiding of the 256-thread version at the
// SAME weight traffic: AB+fW2 read once per 8 rows). Transposed output.
__global__ __launch_bounds__(512) void gk_h12t(const float* __restrict__ xt, const float* __restrict__ xn,
                                               const float* __restrict__ AB, const float* __restrict__ fb1,
                                               const float* __restrict__ fW2, const float* __restrict__ fb2,
                                               float* __restrict__ HrawT) {
  int n0 = blockIdx.x * 8;                 // 256 blocks
  int e  = threadIdx.x & 127;
  int q2 = ((threadIdx.x >> 7) & 3) * 2;   // row pair 0,2,4,6 (wave-uniform)
  __shared__ float stT[DIM][8], snT[DIM][8], h1T[DIM][8];
  {
    int c = threadIdx.x & 31, rq = threadIdx.x >> 5;   // 0..15
    int r = rq & 7;
    const float* src = (rq < 8) ? (xt + (long)(n0 + r) * DIM)
                                : (xn + (long)(n0 + r) * DIM);
    float (*dst)[8] = (rq < 8) ? stT : snT;
    #pragma unroll
    for (int i = 0; i < 4; ++i) {
      int d = c + 32 * i;
      dst[d][r] = src[d];
    }
  }
  __syncthreads();
  float2 acc1 = make_float2(0.f, 0.f);     // rows n0+q2, n0+q2+1, col e
  #pragma unroll 8
  for (int k = 0; k < DIM; ++k) {
    float a = AB[k * DIM + e];
    float b = AB[16384 + k * DIM + e];
    float2 xv = *(const float2*)&stT[k][q2];   // broadcast b64
    float2 nv = *(const float2*)&snT[k][q2];
    acc1.x += xv.x * a + nv.x * b;
    acc1.y += xv.y * a + nv.y * b;
  }
  float b1v = fb1[e];
  float2 h1 = make_float2(fmaxf(acc1.x + b1v, 0.f), fmaxf(acc1.y + b1v, 0.f));
  *(float2*)&h1T[e][q2] = h1;
  __syncthreads();
  float2 acc2 = make_float2(0.f, 0.f);
  #pragma unroll 8
  for (int j = 0; j < DIM; ++j) {
    float wv = fW2[j * DIM + e];
    float2 hv = *(const float2*)&h1T[j][q2];   // broadcast b64
    acc2.x += hv.x * wv;
    acc2.y += hv.y * wv;
  }
  float b2v = fb2[e];
  float2 o = make_float2(acc2.x + b2v, acc2.y + b2v);
  *(float2*)&HrawT[(long)e * NTOT + n0 + q2] = o;   // transposed
}

// ---------------------------------------------------------------- reductions
// fused colstats+softmax (one block/column, column register-resident).
// Block 0 also zeroes Gacc (jsd runs strictly after this kernel).
__global__ __launch_bounds__(256) void colsoft_k(const float* __restrict__ HrawT,
                                                 float* __restrict__ HTp, float* __restrict__ Ecol,
                                                 float* __restrict__ Gacc) {
  int e = blockIdx.x;
  int t = threadIdx.x;
  if (e == 0 && t < DIM) Gacc[t] = 0.f;
  __shared__ float sa[4], sb[4], sc[4];
  float v[8];
  float sum = 0.f, sq = 0.f, mx = -3.4e38f;
  #pragma unroll
  for (int r = 0; r < 8; ++r) {
    float x = HrawT[(long)e * NTOT + t + 256 * r];   // coalesced
    v[r] = x;
    sum += x; sq += x * x; mx = fmaxf(mx, x);
  }
  #pragma unroll
  for (int o = 32; o > 0; o >>= 1) {
    sum += __shfl_down(sum, o);
    sq  += __shfl_down(sq, o);
    mx   = fmaxf(mx, __shfl_down(mx, o));
  }
  if ((t & 63) == 0) { int w = t >> 6; sa[w] = sum; sb[w] = sq; sc[w] = mx; }
  __syncthreads();
  sum = sa[0] + sa[1] + sa[2] + sa[3];
  sq  = sb[0] + sb[1] + sb[2] + sb[3];
  mx  = fmaxf(fmaxf(sc[0], sc[1]), fmaxf(sc[2], sc[3]));
  float mean = sum * (1.f / NTOT);
  float var  = (sq - sum * mean) * (1.f / (NTOT - 1));
  float ia   = 1.f / (sqrtf(fmaxf(var, 0.f)) + 1e-6f);
  float smax = (mx - mean) * ia;
  __syncthreads();

  float den = 0.f;
  #pragma unroll
  for (int r = 0; r < 8; ++r) {
    float s = (v[r] - mean) * ia - smax;
    v[r] = s;
    den += __expf(s);
  }
  #pragma unroll
  for (int o = 32; o > 0; o >>= 1) den += __shfl_down(den, o);
  if ((t & 63) == 0) sa[t >> 6] = den;
  __syncthreads();
  den = sa[0] + sa[1] + sa[2] + sa[3];
  float logden = __logf(den);
  float invden = 1.f / den;
  __syncthreads();

  float ent = 0.f;
  #pragma unroll
  for (int r = 0; r < 8; ++r) {
    float s = v[r];
    float pv = __expf(s) * invden;
    HTp[(long)e * NTOT + t + 256 * r] = pv;
    ent += pv * (s - logden);
  }
  #pragma unroll
  for (int o = 32; o > 0; o >>= 1) ent += __shfl_down(ent, o);
  if ((t & 63) == 0) sa[t >> 6] = ent;
  __syncthreads();
  if (t == 0) Ecol[e] = sa[0] + sa[1] + sa[2] + sa[3];
}

// ---------------------------------------------------------------- jsd + xz (fused launch)
// bid < 576: pairwise-JSD log part (36 tile-pairs x 16 n-splits)
// bid >= 576: Xzs partial H^T x (512 jobs, 32x32 tiles, 2x2 micro — R3-proven)
__global__ __launch_bounds__(256) void jx_k(const float* __restrict__ HTp,
                                            const float* __restrict__ xt, const float* __restrict__ xn,
                                            float* __restrict__ g, float* __restrict__ Xzs) {
  __shared__ union {
    struct { float Ti[JT][JNC + 2], Tj[JT][JNC + 2], red[JT][JT + 1]; } j;   // 17.7 KB
    struct { float As[32][33], Bs[32][36]; } x;                              // 8.8 KB
  } sm;
  int bid = blockIdx.x;
  int tid = threadIdx.x;

  if (bid < 576) {
    // ---- jsd: single JNC-wide chunk per job
    int ny = bid / 36, b = bid - ny * 36;
    int bi = 0, rem = b;
    while (rem >= 8 - bi) { rem -= 8 - bi; ++bi; }
    int bj = bi + rem;                      // bi <= bj
    int n0 = ny * (NTOT / JNSPLIT);         // == ny * JNC
    int ti = tid >> 4, tj = tid & 15;
    bool active = (bi != bj) || (ti < tj);
    int lc = tid >> 4, ln = (tid & 15) * 8;
    const float* si = HTp + (long)(bi * JT + lc) * NTOT + n0 + ln;
    const float* sj = HTp + (long)(bj * JT + lc) * NTOT + n0 + ln;
    #pragma unroll
    for (int r = 0; r < 8; ++r) sm.j.Ti[lc][ln + r] = si[r];
    #pragma unroll
    for (int r = 0; r < 8; ++r) sm.j.Tj[lc][ln + r] = sj[r];
    __syncthreads();
    float acc = 0.f;
    if (active) {
      #pragma unroll 4
      for (int n = 0; n < JNC; ++n) {
        float s = sm.j.Ti[ti][n] + sm.j.Tj[tj][n];
        acc += s * __logf(fmaxf(0.5f * s, 1e-38f));
      }
    }
    sm.j.red[ti][tj] = active ? acc : 0.f;
    __syncthreads();
    if (tid < JT) {
      float s = 0.f;
      #pragma unroll
      for (int q = 0; q < JT; ++q) s += sm.j.red[tid][q];
      atomicAdd(&g[bi * JT + tid], -s);
    } else if (tid < 2 * JT) {
      int c2 = tid - JT;
      float s = 0.f;
      #pragma unroll
      for (int i = 0; i < JT; ++i) s += sm.j.red[i][c2];
      atomicAdd(&g[bj * JT + c2], -s);
    }
  } else {
    // ---- xz: Xzs[bt][split][e][d] = partial sum_n Hsoft[n,e] x[n][d]
    int id = bid - 576;
    int bt = id >> 8;
    int split = (id >> 4) & 15;
    int t16 = id & 15;
    const float* x = bt ? xn : xt;
    float* C = Xzs + ((long)bt * ZSPLIT + split) * 16384;
    int e0 = (t16 & 3) * 32, d0 = (t16 >> 2) * 32;
    int n0 = split * (NTOT / ZSPLIT);
    int col = tid & 31, row = tid >> 5;
    int lr = tid >> 3, lc4 = (tid & 7) * 4;
    int tx = tid & 15, ty = tid >> 4;
    float a00 = 0.f, a01 = 0.f, a10 = 0.f, a11 = 0.f;
    float pa[4]; float4 pb;
    #pragma unroll
    for (int r = 0; r < 4; ++r) pa[r] = HTp[(long)(e0 + row + r * 8) * NTOT + n0 + col];
    pb = *(const float4*)(x + (long)(n0 + lr) * DIM + d0 + lc4);
    for (int nb = 0; nb < NTOT / ZSPLIT; nb += 32) {
      #pragma unroll
      for (int r = 0; r < 4; ++r) sm.x.As[col][row + r * 8] = pa[r];
      *(float4*)&sm.x.Bs[lr][lc4] = pb;
      __syncthreads();
      if (nb + 32 < NTOT / ZSPLIT) {
        #pragma unroll
        for (int r = 0; r < 4; ++r)
          pa[r] = HTp[(long)(e0 + row + r * 8) * NTOT + n0 + nb + 32 + col];
        pb = *(const float4*)(x + (long)(n0 + nb + 32 + lr) * DIM + d0 + lc4);
      }
      #pragma unroll
      for (int nn = 0; nn < 32; ++nn) {
        float e0v = sm.x.As[nn][2*ty], e1v = sm.x.As[nn][2*ty+1];
        float d0v = sm.x.Bs[nn][2*tx], d1v = sm.x.Bs[nn][2*tx+1];
        a00 += e0v * d0v; a01 += e0v * d1v;
        a10 += e1v * d0v; a11 += e1v * d1v;
      }
      __syncthreads();
    }
    int e = e0 + 2 * ty, d = d0 + 2 * tx;
    C[e * DIM + d]           = a00;
    C[e * DIM + d + 1]       = a01;
    C[(e + 1) * DIM + d]     = a10;
    C[(e + 1) * DIM + d + 1] = a11;
  }
}

// Zw[bt][e][d] = w[e] * sum_k (sum_s Xzs[bt][s][e][k]) * theta[k][d]
// w computed per-wave via 64-lane butterfly (no LDS/syncs; proven round 2).
// grid (128, 2), block 128.
__global__ __launch_bounds__(128) void zs_k(const float* __restrict__ Xzs, const float* __restrict__ thT,
                                            const float* __restrict__ thN, const float* __restrict__ g,
                                            const float* __restrict__ Ecol, float* __restrict__ Zw) {
  int e = blockIdx.x, d = threadIdx.x, bt = blockIdx.y;
  float we;
  {
    int l = threadIdx.x & 63;
    float gA = g[l], gB = g[l + 64];
    float eA = Ecol[l], eB = Ecol[l + 64];
    float S = eA + eB;
    #pragma unroll
    for (int o = 32; o > 0; o >>= 1) S += __shfl_xor(S, o);
    float jA = (gA + 126.f * eA + S) * (1.f / 256.f);
    float jB = (gB + 126.f * eB + S) * (1.f / 256.f);
    float sn = jA + jB;
    #pragma unroll
    for (int o = 32; o > 0; o >>= 1) sn += __shfl_xor(sn, o);
    float mean = sn * (1.f / 128.f);
    float dA = jA - mean, dB = jB - mean;
    float q = dA * dA + dB * dB;
    #pragma unroll
    for (int o = 32; o > 0; o >>= 1) q += __shfl_xor(q, o);
    float inv = 1.f / (sqrtf(q * (1.f / 127.f)) + 1e-6f);
    float nA = dA * inv, nB = dB * inv;
    float mx = fmaxf(nA, nB);
    #pragma unroll
    for (int o = 32; o > 0; o >>= 1) mx = fmaxf(mx, __shfl_xor(mx, o));
    float xA = __expf(nA - mx), xB = __expf(nB - mx);
    float den = xA + xB;
    #pragma unroll
    for (int o = 32; o > 0; o >>= 1) den += __shfl_xor(den, o);
    float sel = (e < 64) ? nA : nB;
    float ne = __shfl(sel, e & 63);
    we = __expf(ne - mx) / den;
  }
  const float* src = Xzs + (long)bt * ZSPLIT * 16384 + e * DIM + d;
  const float* th = bt ? thN : thT;
  __shared__ float s[DIM];
  float xv = 0.f;
  #pragma unroll
  for (int sp = 0; sp < ZSPLIT; ++sp) xv += src[sp * 16384];
  s[d] = xv;
  __syncthreads();
  float acc = 0.f;
  #pragma unroll 8
  for (int k = 0; k < DIM; ++k) acc += s[k] * th[(long)k * DIM + d];
  Zw[bt * 16384 + e * DIM + d] = acc * we;
}

// out[n][d] = x[n][d] + elu( sum_e Hsoft[n,e] Zw[e][d] )  (H read from HTp)
// grid (4, 64, 2), block 256. Register double-buffered staging.
__global__ __launch_bounds__(256) void uk_t(const float* __restrict__ HTp, const float* __restrict__ Zw,
                                            const float* __restrict__ xt, const float* __restrict__ xn,
                                            float* __restrict__ out) {
  int bt = blockIdx.z;
  const float* x = bt ? xn : xt;
  const float* B = Zw + bt * 16384;
  float* o = out + (long)bt * NTOT * DIM;
  int d0 = blockIdx.x * 32, n0 = blockIdx.y * 32;
  __shared__ float As[32][33], Bs[32][36];   // As[n][e], Bs[e][d]
  int tid = threadIdx.x, col = tid & 31, row = tid >> 5;
  int lr = tid >> 3, lc4 = (tid & 7) * 4;
  int tx = tid & 15, ty = tid >> 4;
  float a00 = 0.f, a01 = 0.f, a10 = 0.f, a11 = 0.f;
  float pa[4]; float4 pb;
  #pragma unroll
  for (int r = 0; r < 4; ++r) pa[r] = HTp[(long)(row + r * 8) * NTOT + n0 + col];
  pb = *(const float4*)(B + (long)lr * DIM + d0 + lc4);
  for (int eb = 0; eb < DIM; eb += 32) {
    #pragma unroll
    for (int r = 0; r < 4; ++r) As[col][row + r * 8] = pa[r];
    *(float4*)&Bs[lr][lc4] = pb;
    __syncthreads();
    if (eb + 32 < DIM) {
      #pragma unroll
      for (int r = 0; r < 4; ++r)
        pa[r] = HTp[(long)(eb + 32 + row + r * 8) * NTOT + n0 + col];
      pb = *(const float4*)(B + (long)(eb + 32 + lr) * DIM + d0 + lc4);
    }
    #pragma unroll
    for (int ee = 0; ee < 32; ++ee) {
      float x0 = As[2*ty][ee], x1 = As[2*ty+1][ee];
      float b0 = Bs[ee][2*tx], b1 = Bs[ee][2*tx+1];
      a00 += x0 * b0; a01 += x0 * b1;
      a10 += x1 * b0; a11 += x1 * b1;
    }
    __syncthreads();
  }
  int n = n0 + 2 * ty, d = d0 + 2 * tx;
  long i0 = (long)n * DIM + d, i1 = i0 + DIM;
  float e00 = a00 > 0.f ? a00 : expm1f(a00);
  float e01 = a01 > 0.f ? a01 : expm1f(a01);
  float e10 = a10 > 0.f ? a10 : expm1f(a10);
  float e11 = a11 > 0.f ? a11 : expm1f(a11);
  o[i0]     = x[i0]     + e00;
  o[i0 + 1] = x[i0 + 1] + e01;
  o[i1]     = x[i1]     + e10;
  o[i1 + 1] = x[i1 + 1] + e11;
}

// ---------------------------------------------------------------- launcher
extern "C" void kernel_launch(void* const* d_in, const int* in_sizes, int n_in,
                              void* d_out, int out_size, void* d_ws, size_t ws_size,
                              hipStream_t stream) {
  const float* xt = (const float*)d_in[0];   // x_time (f32)
  const float* xn = (const float*)d_in[1];   // x_news
  const float *W1[4], *b1[4], *W2[4], *b2[4];
  for (int k = 0; k < 4; ++k) {           // it, inw, t2n, n2t
    W1[k] = (const float*)d_in[2 + 4*k];
    b1[k] = (const float*)d_in[3 + 4*k];
    W2[k] = (const float*)d_in[4 + 4*k];
    b2[k] = (const float*)d_in[5 + 4*k];
  }
  const float* fW1 = (const float*)d_in[18];
  const float* fb1 = (const float*)d_in[19];
  const float* fW2 = (const float*)d_in[20];
  const float* fb2 = (const float*)d_in[21];
  const float* thT = (const float*)d_in[22];
  const float* thN = (const float*)d_in[23];

  // ws map (floats), peak 3211648 = 12.8 MB (no host-side zeroing needed)
  float* ws    = (float*)d_ws;
  float* Gacc  = ws;                         // [0,128)  zeroed by colsoft block 0
  float* Ecol  = ws + 128;                   // [128,256)
  float* Zw    = ws + 384;                   // [384,33152)
  float* Xzs   = ws + 33152;                 // 2*ZSPLIT*16384 = 524288 -> 557440
  float* Gs    = ws + 557440;                // 4*MSPLIT*16384 = 2097152 -> 2654592
  float* AB    = ws + 2654592;               // 32768 -> 2687360
  float* HrawT = ws + 2687360;               // 262144 -> 2949504 (transposed [e][n])
  float* HTp   = ws + 2949504;               // 262144 -> 3211648

  float* out = (float*)d_out;                // f32 output, [time | news]

  P4 Xs  = {{xt, xn, xn, xt}};
  P4 W1s = {{W1[0], W1[1], W1[2], W1[3]}};
  P4 B1s = {{b1[0], b1[1], b1[2], b1[3]}};
  P4 W2s = {{W2[0], W2[1], W2[2], W2[3]}};
  P4 B2s = {{b2[0], b2[1], b2[2], b2[3]}};

  gk_mlp1t<<<dim3(4, MSPLIT, 4), 256, 0, stream>>>(Xs, W1s, Gs);
  gk_mab  <<<128, 256, 0, stream>>>(Gs, B1s, W2s, B2s, fW1, AB);
  gk_h12t <<<256, 512, 0, stream>>>(xt, xn, AB, fb1, fW2, fb2, HrawT);

  colsoft_k<<<DIM, 256, 0, stream>>>(HrawT, HTp, Ecol, Gacc);

  jx_k<<<576 + 512, 256, 0, stream>>>(HTp, xt, xn, Gacc, Xzs);

  zs_k<<<dim3(128, 2), 128, 0, stream>>>(Xzs, thT, thN, Gacc, Ecol, Zw);
  uk_t<<<dim3(4, 64, 2), 256, 0, stream>>>(HTp, Zw, xt, xn, out);

  (void)in_sizes; (void)n_in; (void)out_size; (void)ws_size;
}

// Round 6
// 172.756 us; speedup vs baseline: 1.0939x; 1.0869x over previous
//
#include <hip/hip_runtime.h>
#include <hip/hip_bf16.h>
#include <math.h>

#define NTOT 2048   // N*T
#define DIM  128    // D == E1
#define MSPLIT 16   // split-K for gk_mlp1t (16 tiles x 16 splits x 4 k = 1024 blocks)
#define ZSPLIT 16   // split-K for xz stage (512 jobs at 32x32 tiles)
#define JT 16       // jsd tile width (columns)
#define JNC 128     // jsd n-chunk in LDS
#define JNSPLIT 16  // jsd n splits (36*16 = 576 jobs, single chunk each)

struct P4 { const float* p[4]; };

// ---------------------------------------------------------------- H pipeline
// Gs[k][split] = partial X_k^T @ W1_k  (no atomics; consumer sums splits)
// R3-proven config: 32x32 tile, 2x2 micro, K=128/block, 1024 blocks (4/CU).
__global__ __launch_bounds__(256) void gk_mlp1t(P4 X, P4 W1, float* __restrict__ Gs) {
  int k = blockIdx.z;
  int m0 = (blockIdx.x & 3) * 32;
  int e0 = (blockIdx.x >> 2) * 32;
  int split = blockIdx.y;
  int n0 = split * (NTOT / MSPLIT);
  const float* Xp = X.p[k];
  const float* Wp = W1.p[k];
  __shared__ float Xs[32][36], Ws[32][36];   // 36: row-aligned for b128 stores
  int tid = threadIdx.x;
  int lr = tid >> 3;              // load row 0..31
  int lc = (tid & 7) * 4;         // load col 0,4,..28
  int tx = tid & 15, ty = tid >> 4;
  float a00 = 0.f, a01 = 0.f, a10 = 0.f, a11 = 0.f;
  long g0 = (long)(n0 + lr) * DIM;
  float4 xv = *(const float4*)(Xp + g0 + m0 + lc);   // prefetch tile 0
  float4 wv = *(const float4*)(Wp + g0 + e0 + lc);
  for (int nb = 0; nb < NTOT / MSPLIT; nb += 32) {
    *(float4*)&Xs[lr][lc] = xv;
    *(float4*)&Ws[lr][lc] = wv;
    __syncthreads();
    if (nb + 32 < NTOT / MSPLIT) {                   // prefetch tile nb+32
      long gn = (long)(n0 + nb + 32 + lr) * DIM;
      xv = *(const float4*)(Xp + gn + m0 + lc);
      wv = *(const float4*)(Wp + gn + e0 + lc);
    }
    #pragma unroll
    for (int nn = 0; nn < 32; ++nn) {
      float x0 = Xs[nn][2*ty], x1 = Xs[nn][2*ty+1];
      float w0 = Ws[nn][2*tx], w1 = Ws[nn][2*tx+1];
      a00 += x0 * w0; a01 += x0 * w1;
      a10 += x1 * w0; a11 += x1 * w1;
    }
    __syncthreads();
  }
  float* Gk = Gs + ((long)k * MSPLIT + split) * 16384;
  int m = m0 + 2 * ty, e = e0 + 2 * tx;
  Gk[m * DIM + e]           = a00;
  Gk[m * DIM + e + 1]       = a01;
  Gk[(m + 1) * DIM + e]     = a10;
  Gk[(m + 1) * DIM + e + 1] = a11;
}

// Fused gk_mlp2 + gk_ab (one launch, no Mk round-trip). grid 128, block 256
__global__ __launch_bounds__(256) void gk_mab(const float* __restrict__ Gs, P4 B1, P4 W2, P4 B2,
                                              const float* __restrict__ fW1, float* __restrict__ AB) {
  int m = blockIdx.x;
  int e = threadIdx.x & 127;
  int half = threadIdx.x >> 7;      // 0,1
  int k0 = half, k1 = half + 2;
  __shared__ float rk[4][DIM];      // relu(sum_s Gs + b1)
  __shared__ float mk[4][DIM];      // M rows
  {
    const float* G0 = Gs + (long)k0 * MSPLIT * 16384 + m * DIM + e;
    const float* G1 = Gs + (long)k1 * MSPLIT * 16384 + m * DIM + e;
    float s0 = 0.f, s1 = 0.f;
    #pragma unroll
    for (int s = 0; s < MSPLIT; ++s) { s0 += G0[s * 16384]; s1 += G1[s * 16384]; }
    rk[k0][e] = fmaxf(s0 + B1.p[k0][e], 0.f);
    rk[k1][e] = fmaxf(s1 + B1.p[k1][e], 0.f);
  }
  __syncthreads();
  {
    const float* Wa = W2.p[k0];
    const float* Wb = W2.p[k1];
    float a0 = B2.p[k0][e], a1 = B2.p[k1][e];
    #pragma unroll 8
    for (int j = 0; j < DIM; ++j) {
      a0 += rk[k0][j] * Wa[j * DIM + e];
      a1 += rk[k1][j] * Wb[j * DIM + e];
    }
    mk[k0][e] = a0;
    mk[k1][e] = a1;
  }
  __syncthreads();
  const float* Ma = mk[half];           // h=0: it ; h=1: inw
  const float* Mb = mk[half + 2];       // h=0: t2n; h=1: n2t
  const float* W0 = fW1 + (half == 0 ? 0 : 128) * DIM;
  const float* W1p = fW1 + (half == 0 ? 256 : 384) * DIM;
  float acc = 0.f;
  #pragma unroll 8
  for (int j = 0; j < DIM; ++j)
    acc += Ma[j] * W0[j * DIM + e] + Mb[j] * W1p[j * DIM + e];
  AB[(long)half * 16384 + m * DIM + e] = acc;
}

// Fused H1+H2, 8 rows per block, 512 threads (256 blocks -> 8 waves/block =
// 2 waves/SIMD; same weight traffic as 8-row/256t, double latency hiding).
// Transposed output HrawT[e][n]. Numerics validated in R5.
__global__ __launch_bounds__(512) void gk_h12t(const float* __restrict__ xt, const float* __restrict__ xn,
                                               const float* __restrict__ AB, const float* __restrict__ fb1,
                                               const float* __restrict__ fW2, const float* __restrict__ fb2,
                                               float* __restrict__ HrawT) {
  int n0 = blockIdx.x * 8;                 // 256 blocks
  int e  = threadIdx.x & 127;
  int q2 = ((threadIdx.x >> 7) & 3) * 2;   // row pair 0,2,4,6 (wave-uniform)
  __shared__ float stT[DIM][8], snT[DIM][8], h1T[DIM][8];
  {
    int c = threadIdx.x & 31, rq = threadIdx.x >> 5;   // 0..15
    int r = rq & 7;
    const float* src = (rq < 8) ? (xt + (long)(n0 + r) * DIM)
                                : (xn + (long)(n0 + r) * DIM);
    float (*dst)[8] = (rq < 8) ? stT : snT;
    #pragma unroll
    for (int i = 0; i < 4; ++i) {
      int d = c + 32 * i;
      dst[d][r] = src[d];
    }
  }
  __syncthreads();
  float2 acc1 = make_float2(0.f, 0.f);     // rows n0+q2, n0+q2+1, col e
  #pragma unroll 8
  for (int k = 0; k < DIM; ++k) {
    float a = AB[k * DIM + e];
    float b = AB[16384 + k * DIM + e];
    float2 xv = *(const float2*)&stT[k][q2];   // broadcast b64
    float2 nv = *(const float2*)&snT[k][q2];
    acc1.x += xv.x * a + nv.x * b;
    acc1.y += xv.y * a + nv.y * b;
  }
  float b1v = fb1[e];
  float2 h1 = make_float2(fmaxf(acc1.x + b1v, 0.f), fmaxf(acc1.y + b1v, 0.f));
  *(float2*)&h1T[e][q2] = h1;
  __syncthreads();
  float2 acc2 = make_float2(0.f, 0.f);
  #pragma unroll 8
  for (int j = 0; j < DIM; ++j) {
    float wv = fW2[j * DIM + e];
    float2 hv = *(const float2*)&h1T[j][q2];   // broadcast b64
    acc2.x += hv.x * wv;
    acc2.y += hv.y * wv;
  }
  float b2v = fb2[e];
  float2 o = make_float2(acc2.x + b2v, acc2.y + b2v);
  *(float2*)&HrawT[(long)e * NTOT + n0 + q2] = o;   // transposed
}

// ---------------------------------------------------------------- reductions
// fused colstats+softmax (one block/column, column register-resident).
// Block 0 also zeroes Gacc (jsd runs strictly after this kernel).
__global__ __launch_bounds__(256) void colsoft_k(const float* __restrict__ HrawT,
                                                 float* __restrict__ HTp, float* __restrict__ Ecol,
                                                 float* __restrict__ Gacc) {
  int e = blockIdx.x;
  int t = threadIdx.x;
  if (e == 0 && t < DIM) Gacc[t] = 0.f;
  __shared__ float sa[4], sb[4], sc[4];
  float v[8];
  float sum = 0.f, sq = 0.f, mx = -3.4e38f;
  #pragma unroll
  for (int r = 0; r < 8; ++r) {
    float x = HrawT[(long)e * NTOT + t + 256 * r];   // coalesced
    v[r] = x;
    sum += x; sq += x * x; mx = fmaxf(mx, x);
  }
  #pragma unroll
  for (int o = 32; o > 0; o >>= 1) {
    sum += __shfl_down(sum, o);
    sq  += __shfl_down(sq, o);
    mx   = fmaxf(mx, __shfl_down(mx, o));
  }
  if ((t & 63) == 0) { int w = t >> 6; sa[w] = sum; sb[w] = sq; sc[w] = mx; }
  __syncthreads();
  sum = sa[0] + sa[1] + sa[2] + sa[3];
  sq  = sb[0] + sb[1] + sb[2] + sb[3];
  mx  = fmaxf(fmaxf(sc[0], sc[1]), fmaxf(sc[2], sc[3]));
  float mean = sum * (1.f / NTOT);
  float var  = (sq - sum * mean) * (1.f / (NTOT - 1));
  float ia   = 1.f / (sqrtf(fmaxf(var, 0.f)) + 1e-6f);
  float smax = (mx - mean) * ia;
  __syncthreads();

  float den = 0.f;
  #pragma unroll
  for (int r = 0; r < 8; ++r) {
    float s = (v[r] - mean) * ia - smax;
    v[r] = s;
    den += __expf(s);
  }
  #pragma unroll
  for (int o = 32; o > 0; o >>= 1) den += __shfl_down(den, o);
  if ((t & 63) == 0) sa[t >> 6] = den;
  __syncthreads();
  den = sa[0] + sa[1] + sa[2] + sa[3];
  float logden = __logf(den);
  float invden = 1.f / den;
  __syncthreads();

  float ent = 0.f;
  #pragma unroll
  for (int r = 0; r < 8; ++r) {
    float s = v[r];
    float pv = __expf(s) * invden;
    HTp[(long)e * NTOT + t + 256 * r] = pv;
    ent += pv * (s - logden);
  }
  #pragma unroll
  for (int o = 32; o > 0; o >>= 1) ent += __shfl_down(ent, o);
  if ((t & 63) == 0) sa[t >> 6] = ent;
  __syncthreads();
  if (t == 0) Ecol[e] = sa[0] + sa[1] + sa[2] + sa[3];
}

// ---------------------------------------------------------------- jsd + xz (fused launch)
// bid < 512: Xzs partial H^T x (longer jobs dispatched FIRST for shorter tail)
// bid >= 512: pairwise-JSD log part (36 tile-pairs x 16 n-splits)
__global__ __launch_bounds__(256) void jx_k(const float* __restrict__ HTp,
                                            const float* __restrict__ xt, const float* __restrict__ xn,
                                            float* __restrict__ g, float* __restrict__ Xzs) {
  __shared__ union {
    struct { float Ti[JT][JNC + 2], Tj[JT][JNC + 2], red[JT][JT + 1]; } j;   // 17.7 KB
    struct { float As[32][33], Bs[32][36]; } x;                              // 8.8 KB
  } sm;
  int bid = blockIdx.x;
  int tid = threadIdx.x;

  if (bid >= 512) {
    // ---- jsd: single JNC-wide chunk per job
    int jj = bid - 512;
    int ny = jj / 36, b = jj - ny * 36;
    int bi = 0, rem = b;
    while (rem >= 8 - bi) { rem -= 8 - bi; ++bi; }
    int bj = bi + rem;                      // bi <= bj
    int n0 = ny * (NTOT / JNSPLIT);         // == ny * JNC
    int ti = tid >> 4, tj = tid & 15;
    bool active = (bi != bj) || (ti < tj);
    int lc = tid >> 4, ln = (tid & 15) * 8;
    const float* si = HTp + (long)(bi * JT + lc) * NTOT + n0 + ln;
    const float* sj = HTp + (long)(bj * JT + lc) * NTOT + n0 + ln;
    #pragma unroll
    for (int r = 0; r < 8; ++r) sm.j.Ti[lc][ln + r] = si[r];
    #pragma unroll
    for (int r = 0; r < 8; ++r) sm.j.Tj[lc][ln + r] = sj[r];
    __syncthreads();
    float acc = 0.f;
    if (active) {
      #pragma unroll 4
      for (int n = 0; n < JNC; ++n) {
        float s = sm.j.Ti[ti][n] + sm.j.Tj[tj][n];
        acc += s * __logf(fmaxf(0.5f * s, 1e-38f));
      }
    }
    sm.j.red[ti][tj] = active ? acc : 0.f;
    __syncthreads();
    if (tid < JT) {
      float s = 0.f;
      #pragma unroll
      for (int q = 0; q < JT; ++q) s += sm.j.red[tid][q];
      atomicAdd(&g[bi * JT + tid], -s);
    } else if (tid < 2 * JT) {
      int c2 = tid - JT;
      float s = 0.f;
      #pragma unroll
      for (int i = 0; i < JT; ++i) s += sm.j.red[i][c2];
      atomicAdd(&g[bj * JT + c2], -s);
    }
  } else {
    // ---- xz: Xzs[bt][split][e][d] = partial sum_n Hsoft[n,e] x[n][d]
    int id = bid;
    int bt = id >> 8;
    int split = (id >> 4) & 15;
    int t16 = id & 15;
    const float* x = bt ? xn : xt;
    float* C = Xzs + ((long)bt * ZSPLIT + split) * 16384;
    int e0 = (t16 & 3) * 32, d0 = (t16 >> 2) * 32;
    int n0 = split * (NTOT / ZSPLIT);
    int col = tid & 31, row = tid >> 5;
    int lr = tid >> 3, lc4 = (tid & 7) * 4;
    int tx = tid & 15, ty = tid >> 4;
    float a00 = 0.f, a01 = 0.f, a10 = 0.f, a11 = 0.f;
    float pa[4]; float4 pb;
    #pragma unroll
    for (int r = 0; r < 4; ++r) pa[r] = HTp[(long)(e0 + row + r * 8) * NTOT + n0 + col];
    pb = *(const float4*)(x + (long)(n0 + lr) * DIM + d0 + lc4);
    for (int nb = 0; nb < NTOT / ZSPLIT; nb += 32) {
      #pragma unroll
      for (int r = 0; r < 4; ++r) sm.x.As[col][row + r * 8] = pa[r];
      *(float4*)&sm.x.Bs[lr][lc4] = pb;
      __syncthreads();
      if (nb + 32 < NTOT / ZSPLIT) {
        #pragma unroll
        for (int r = 0; r < 4; ++r)
          pa[r] = HTp[(long)(e0 + row + r * 8) * NTOT + n0 + nb + 32 + col];
        pb = *(const float4*)(x + (long)(n0 + nb + 32 + lr) * DIM + d0 + lc4);
      }
      #pragma unroll
      for (int nn = 0; nn < 32; ++nn) {
        float e0v = sm.x.As[nn][2*ty], e1v = sm.x.As[nn][2*ty+1];
        float d0v = sm.x.Bs[nn][2*tx], d1v = sm.x.Bs[nn][2*tx+1];
        a00 += e0v * d0v; a01 += e0v * d1v;
        a10 += e1v * d0v; a11 += e1v * d1v;
      }
      __syncthreads();
    }
    int e = e0 + 2 * ty, d = d0 + 2 * tx;
    C[e * DIM + d]           = a00;
    C[e * DIM + d + 1]       = a01;
    C[(e + 1) * DIM + d]     = a10;
    C[(e + 1) * DIM + d + 1] = a11;
  }
}

// Zw[bt][e][d] = w[e] * sum_k (sum_s Xzs[bt][s][e][k]) * theta[k][d]
// w computed per-wave via 64-lane butterfly (no LDS/syncs; proven round 2).
// grid (128, 2), block 128.
__global__ __launch_bounds__(128) void zs_k(const float* __restrict__ Xzs, const float* __restrict__ thT,
                                            const float* __restrict__ thN, const float* __restrict__ g,
                                            const float* __restrict__ Ecol, float* __restrict__ Zw) {
  int e = blockIdx.x, d = threadIdx.x, bt = blockIdx.y;
  float we;
  {
    int l = threadIdx.x & 63;
    float gA = g[l], gB = g[l + 64];
    float eA = Ecol[l], eB = Ecol[l + 64];
    float S = eA + eB;
    #pragma unroll
    for (int o = 32; o > 0; o >>= 1) S += __shfl_xor(S, o);
    float jA = (gA + 126.f * eA + S) * (1.f / 256.f);
    float jB = (gB + 126.f * eB + S) * (1.f / 256.f);
    float sn = jA + jB;
    #pragma unroll
    for (int o = 32; o > 0; o >>= 1) sn += __shfl_xor(sn, o);
    float mean = sn * (1.f / 128.f);
    float dA = jA - mean, dB = jB - mean;
    float q = dA * dA + dB * dB;
    #pragma unroll
    for (int o = 32; o > 0; o >>= 1) q += __shfl_xor(q, o);
    float inv = 1.f / (sqrtf(q * (1.f / 127.f)) + 1e-6f);
    float nA = dA * inv, nB = dB * inv;
    float mx = fmaxf(nA, nB);
    #pragma unroll
    for (int o = 32; o > 0; o >>= 1) mx = fmaxf(mx, __shfl_xor(mx, o));
    float xA = __expf(nA - mx), xB = __expf(nB - mx);
    float den = xA + xB;
    #pragma unroll
    for (int o = 32; o > 0; o >>= 1) den += __shfl_xor(den, o);
    float sel = (e < 64) ? nA : nB;
    float ne = __shfl(sel, e & 63);
    we = __expf(ne - mx) / den;
  }
  const float* src = Xzs + (long)bt * ZSPLIT * 16384 + e * DIM + d;
  const float* th = bt ? thN : thT;
  __shared__ float s[DIM];
  float xv = 0.f;
  #pragma unroll
  for (int sp = 0; sp < ZSPLIT; ++sp) xv += src[sp * 16384];
  s[d] = xv;
  __syncthreads();
  float acc = 0.f;
  #pragma unroll 8
  for (int k = 0; k < DIM; ++k) acc += s[k] * th[(long)k * DIM + d];
  Zw[bt * 16384 + e * DIM + d] = acc * we;
}

// out[n][d] = x[n][d] + elu( sum_e Hsoft[n,e] Zw[e][d] )  (H read from HTp)
// grid (4, 64, 2), block 256. Register double-buffered staging.
__global__ __launch_bounds__(256) void uk_t(const float* __restrict__ HTp, const float* __restrict__ Zw,
                                            const float* __restrict__ xt, const float* __restrict__ xn,
                                            float* __restrict__ out) {
  int bt = blockIdx.z;
  const float* x = bt ? xn : xt;
  const float* B = Zw + bt * 16384;
  float* o = out + (long)bt * NTOT * DIM;
  int d0 = blockIdx.x * 32, n0 = blockIdx.y * 32;
  __shared__ float As[32][33], Bs[32][36];   // As[n][e], Bs[e][d]
  int tid = threadIdx.x, col = tid & 31, row = tid >> 5;
  int lr = tid >> 3, lc4 = (tid & 7) * 4;
  int tx = tid & 15, ty = tid >> 4;
  float a00 = 0.f, a01 = 0.f, a10 = 0.f, a11 = 0.f;
  float pa[4]; float4 pb;
  #pragma unroll
  for (int r = 0; r < 4; ++r) pa[r] = HTp[(long)(row + r * 8) * NTOT + n0 + col];
  pb = *(const float4*)(B + (long)lr * DIM + d0 + lc4);
  for (int eb = 0; eb < DIM; eb += 32) {
    #pragma unroll
    for (int r = 0; r < 4; ++r) As[col][row + r * 8] = pa[r];
    *(float4*)&Bs[lr][lc4] = pb;
    __syncthreads();
    if (eb + 32 < DIM) {
      #pragma unroll
      for (int r = 0; r < 4; ++r)
        pa[r] = HTp[(long)(eb + 32 + row + r * 8) * NTOT + n0 + col];
      pb = *(const float4*)(B + (long)(eb + 32 + lr) * DIM + d0 + lc4);
    }
    #pragma unroll
    for (int ee = 0; ee < 32; ++ee) {
      float x0 = As[2*ty][ee], x1 = As[2*ty+1][ee];
      float b0 = Bs[ee][2*tx], b1 = Bs[ee][2*tx+1];
      a00 += x0 * b0; a01 += x0 * b1;
      a10 += x1 * b0; a11 += x1 * b1;
    }
    __syncthreads();
  }
  int n = n0 + 2 * ty, d = d0 + 2 * tx;
  long i0 = (long)n * DIM + d, i1 = i0 + DIM;
  float e00 = a00 > 0.f ? a00 : expm1f(a00);
  float e01 = a01 > 0.f ? a01 : expm1f(a01);
  float e10 = a10 > 0.f ? a10 : expm1f(a10);
  float e11 = a11 > 0.f ? a11 : expm1f(a11);
  o[i0]     = x[i0]     + e00;
  o[i0 + 1] = x[i0 + 1] + e01;
  o[i1]     = x[i1]     + e10;
  o[i1 + 1] = x[i1 + 1] + e11;
}

// ---------------------------------------------------------------- launcher
extern "C" void kernel_launch(void* const* d_in, const int* in_sizes, int n_in,
                              void* d_out, int out_size, void* d_ws, size_t ws_size,
                              hipStream_t stream) {
  const float* xt = (const float*)d_in[0];   // x_time (f32)
  const float* xn = (const float*)d_in[1];   // x_news
  const float *W1[4], *b1[4], *W2[4], *b2[4];
  for (int k = 0; k < 4; ++k) {           // it, inw, t2n, n2t
    W1[k] = (const float*)d_in[2 + 4*k];
    b1[k] = (const float*)d_in[3 + 4*k];
    W2[k] = (const float*)d_in[4 + 4*k];
    b2[k] = (const float*)d_in[5 + 4*k];
  }
  const float* fW1 = (const float*)d_in[18];
  const float* fb1 = (const float*)d_in[19];
  const float* fW2 = (const float*)d_in[20];
  const float* fb2 = (const float*)d_in[21];
  const float* thT = (const float*)d_in[22];
  const float* thN = (const float*)d_in[23];

  // ws map (floats), peak 2163072 = 8.65 MB (no host-side zeroing needed)
  float* ws    = (float*)d_ws;
  float* Gacc  = ws;                         // [0,128)  zeroed by colsoft block 0
  float* Ecol  = ws + 128;                   // [128,256)
  float* Zw    = ws + 384;                   // [384,33152)
  float* Xzs   = ws + 33152;                 // 2*ZSPLIT*16384 = 524288 -> 557440
  float* Gs    = ws + 557440;                // 4*MSPLIT*16384 = 1048576 -> 1606016
  float* AB    = ws + 1606016;               // 32768 -> 1638784
  float* HrawT = ws + 1638784;               // 262144 -> 1900928 (transposed [e][n])
  float* HTp   = ws + 1900928;               // 262144 -> 2163072

  float* out = (float*)d_out;                // f32 output, [time | news]

  P4 Xs  = {{xt, xn, xn, xt}};
  P4 W1s = {{W1[0], W1[1], W1[2], W1[3]}};
  P4 B1s = {{b1[0], b1[1], b1[2], b1[3]}};
  P4 W2s = {{W2[0], W2[1], W2[2], W2[3]}};
  P4 B2s = {{b2[0], b2[1], b2[2], b2[3]}};

  gk_mlp1t<<<dim3(16, MSPLIT, 4), 256, 0, stream>>>(Xs, W1s, Gs);
  gk_mab  <<<128, 256, 0, stream>>>(Gs, B1s, W2s, B2s, fW1, AB);
  gk_h12t <<<256, 512, 0, stream>>>(xt, xn, AB, fb1, fW2, fb2, HrawT);

  colsoft_k<<<DIM, 256, 0, stream>>>(HrawT, HTp, Ecol, Gacc);

  jx_k<<<512 + 576, 256, 0, stream>>>(HTp, xt, xn, Gacc, Xzs);

  zs_k<<<dim3(128, 2), 128, 0, stream>>>(Xzs, thT, thN, Gacc, Ecol, Zw);
  uk_t<<<dim3(4, 64, 2), 256, 0, stream>>>(HTp, Zw, xt, xn, out);

  (void)in_sizes; (void)n_in; (void)out_size; (void)ws_size;
}

// Round 7
// 169.035 us; speedup vs baseline: 1.1179x; 1.0220x over previous
//
#include <hip/hip_runtime.h>
#include <hip/hip_bf16.h>
#include <math.h>

#define NTOT 2048   // N*T
#define DIM  128    // D == E1
#define MSPLIT 16   // split-K for gk_mlp1t (16 tiles x 16 splits x 4 k = 1024 blocks)
#define ZSPLIT 16   // split-K for xz stage (512 jobs at 32x32 tiles)
#define JT 16       // jsd tile width (columns)
#define JNC 128     // jsd n-chunk in LDS
#define JNSPLIT 16  // jsd n splits (36*16 = 576 jobs, single chunk each)

struct P4 { const float* p[4]; };

// ---------------------------------------------------------------- H pipeline
// Gs[k][split] = partial X_k^T @ W1_k  (no atomics; consumer sums splits)
// R3-proven config: 32x32 tile, 2x2 micro, K=128/block, 1024 blocks (4/CU).
__global__ __launch_bounds__(256) void gk_mlp1t(P4 X, P4 W1, float* __restrict__ Gs) {
  int k = blockIdx.z;
  int m0 = (blockIdx.x & 3) * 32;
  int e0 = (blockIdx.x >> 2) * 32;
  int split = blockIdx.y;
  int n0 = split * (NTOT / MSPLIT);
  const float* Xp = X.p[k];
  const float* Wp = W1.p[k];
  __shared__ float Xs[32][36], Ws[32][36];   // 36: row-aligned for b128 stores
  int tid = threadIdx.x;
  int lr = tid >> 3;              // load row 0..31
  int lc = (tid & 7) * 4;         // load col 0,4,..28
  int tx = tid & 15, ty = tid >> 4;
  float a00 = 0.f, a01 = 0.f, a10 = 0.f, a11 = 0.f;
  long g0 = (long)(n0 + lr) * DIM;
  float4 xv = *(const float4*)(Xp + g0 + m0 + lc);   // prefetch tile 0
  float4 wv = *(const float4*)(Wp + g0 + e0 + lc);
  for (int nb = 0; nb < NTOT / MSPLIT; nb += 32) {
    *(float4*)&Xs[lr][lc] = xv;
    *(float4*)&Ws[lr][lc] = wv;
    __syncthreads();
    if (nb + 32 < NTOT / MSPLIT) {                   // prefetch tile nb+32
      long gn = (long)(n0 + nb + 32 + lr) * DIM;
      xv = *(const float4*)(Xp + gn + m0 + lc);
      wv = *(const float4*)(Wp + gn + e0 + lc);
    }
    #pragma unroll
    for (int nn = 0; nn < 32; ++nn) {
      float x0 = Xs[nn][2*ty], x1 = Xs[nn][2*ty+1];
      float w0 = Ws[nn][2*tx], w1 = Ws[nn][2*tx+1];
      a00 += x0 * w0; a01 += x0 * w1;
      a10 += x1 * w0; a11 += x1 * w1;
    }
    __syncthreads();
  }
  float* Gk = Gs + ((long)k * MSPLIT + split) * 16384;
  int m = m0 + 2 * ty, e = e0 + 2 * tx;
  Gk[m * DIM + e]           = a00;
  Gk[m * DIM + e + 1]       = a01;
  Gk[(m + 1) * DIM + e]     = a10;
  Gk[(m + 1) * DIM + e + 1] = a11;
}

// Fused gk_mlp2 + gk_ab, 512 threads: quarter q owns k=q for the split-sum and
// M-dot; then quarters split the AB j-loop in halves (h=q&1 output, jh=q>>1
// j-half) and combine via LDS. Serial path ~halved vs 256t. grid 128.
__global__ __launch_bounds__(512) void gk_mab(const float* __restrict__ Gs, P4 B1, P4 W2, P4 B2,
                                              const float* __restrict__ fW1, float* __restrict__ AB) {
  int m = blockIdx.x;
  int e = threadIdx.x & 127;
  int q = threadIdx.x >> 7;         // 0..3
  __shared__ float rk[4][DIM];      // relu(sum_s Gs + b1)
  __shared__ float mk[4][DIM];      // M rows
  __shared__ float part[4][DIM];    // AB partials [q = jh*2+h][e]
  {
    const float* G0 = Gs + (long)q * MSPLIT * 16384 + m * DIM + e;
    float s0 = 0.f;
    #pragma unroll
    for (int s = 0; s < MSPLIT; ++s) s0 += G0[s * 16384];
    rk[q][e] = fmaxf(s0 + B1.p[q][e], 0.f);
  }
  __syncthreads();
  {
    const float* Wq = W2.p[q];
    float a0 = B2.p[q][e];
    #pragma unroll 8
    for (int j = 0; j < DIM; ++j) a0 += rk[q][j] * Wq[j * DIM + e];
    mk[q][e] = a0;
  }
  __syncthreads();
  {
    int h = q & 1, jh = q >> 1;
    const float* Ma = mk[h];            // h=0: it ; h=1: inw
    const float* Mb = mk[h + 2];        // h=0: t2n; h=1: n2t
    const float* W0 = fW1 + (h == 0 ? 0 : 128) * DIM;
    const float* W1p = fW1 + (h == 0 ? 256 : 384) * DIM;
    float acc = 0.f;
    int j0 = jh * 64;
    #pragma unroll 8
    for (int j = j0; j < j0 + 64; ++j)
      acc += Ma[j] * W0[j * DIM + e] + Mb[j] * W1p[j * DIM + e];
    part[q][e] = acc;
  }
  __syncthreads();
  if (q < 2)                            // q == h here
    AB[(long)q * 16384 + m * DIM + e] = part[q][e] + part[q + 2][e];
}

// Fused H1+H2, 8 rows per block, 512 threads (256 blocks -> 8 waves/block =
// 2 waves/SIMD; same weight traffic as 8-row/256t, double latency hiding).
// Transposed output HrawT[e][n]. Numerics validated in R5.
__global__ __launch_bounds__(512) void gk_h12t(const float* __restrict__ xt, const float* __restrict__ xn,
                                               const float* __restrict__ AB, const float* __restrict__ fb1,
                                               const float* __restrict__ fW2, const float* __restrict__ fb2,
                                               float* __restrict__ HrawT) {
  int n0 = blockIdx.x * 8;                 // 256 blocks
  int e  = threadIdx.x & 127;
  int q2 = ((threadIdx.x >> 7) & 3) * 2;   // row pair 0,2,4,6 (wave-uniform)
  __shared__ float stT[DIM][8], snT[DIM][8], h1T[DIM][8];
  {
    int c = threadIdx.x & 31, rq = threadIdx.x >> 5;   // 0..15
    int r = rq & 7;
    const float* src = (rq < 8) ? (xt + (long)(n0 + r) * DIM)
                                : (xn + (long)(n0 + r) * DIM);
    float (*dst)[8] = (rq < 8) ? stT : snT;
    #pragma unroll
    for (int i = 0; i < 4; ++i) {
      int d = c + 32 * i;
      dst[d][r] = src[d];
    }
  }
  __syncthreads();
  float2 acc1 = make_float2(0.f, 0.f);     // rows n0+q2, n0+q2+1, col e
  #pragma unroll 8
  for (int k = 0; k < DIM; ++k) {
    float a = AB[k * DIM + e];
    float b = AB[16384 + k * DIM + e];
    float2 xv = *(const float2*)&stT[k][q2];   // broadcast b64
    float2 nv = *(const float2*)&snT[k][q2];
    acc1.x += xv.x * a + nv.x * b;
    acc1.y += xv.y * a + nv.y * b;
  }
  float b1v = fb1[e];
  float2 h1 = make_float2(fmaxf(acc1.x + b1v, 0.f), fmaxf(acc1.y + b1v, 0.f));
  *(float2*)&h1T[e][q2] = h1;
  __syncthreads();
  float2 acc2 = make_float2(0.f, 0.f);
  #pragma unroll 8
  for (int j = 0; j < DIM; ++j) {
    float wv = fW2[j * DIM + e];
    float2 hv = *(const float2*)&h1T[j][q2];   // broadcast b64
    acc2.x += hv.x * wv;
    acc2.y += hv.y * wv;
  }
  float b2v = fb2[e];
  float2 o = make_float2(acc2.x + b2v, acc2.y + b2v);
  *(float2*)&HrawT[(long)e * NTOT + n0 + q2] = o;   // transposed
}

// ---------------------------------------------------------------- reductions
// fused colstats+softmax (one block/column, column register-resident).
// Block 0 also zeroes Gacc (jsd runs strictly after this kernel).
__global__ __launch_bounds__(256) void colsoft_k(const float* __restrict__ HrawT,
                                                 float* __restrict__ HTp, float* __restrict__ Ecol,
                                                 float* __restrict__ Gacc) {
  int e = blockIdx.x;
  int t = threadIdx.x;
  if (e == 0 && t < DIM) Gacc[t] = 0.f;
  __shared__ float sa[4], sb[4], sc[4];
  float v[8];
  float sum = 0.f, sq = 0.f, mx = -3.4e38f;
  #pragma unroll
  for (int r = 0; r < 8; ++r) {
    float x = HrawT[(long)e * NTOT + t + 256 * r];   // coalesced
    v[r] = x;
    sum += x; sq += x * x; mx = fmaxf(mx, x);
  }
  #pragma unroll
  for (int o = 32; o > 0; o >>= 1) {
    sum += __shfl_down(sum, o);
    sq  += __shfl_down(sq, o);
    mx   = fmaxf(mx, __shfl_down(mx, o));
  }
  if ((t & 63) == 0) { int w = t >> 6; sa[w] = sum; sb[w] = sq; sc[w] = mx; }
  __syncthreads();
  sum = sa[0] + sa[1] + sa[2] + sa[3];
  sq  = sb[0] + sb[1] + sb[2] + sb[3];
  mx  = fmaxf(fmaxf(sc[0], sc[1]), fmaxf(sc[2], sc[3]));
  float mean = sum * (1.f / NTOT);
  float var  = (sq - sum * mean) * (1.f / (NTOT - 1));
  float ia   = 1.f / (sqrtf(fmaxf(var, 0.f)) + 1e-6f);
  float smax = (mx - mean) * ia;
  __syncthreads();

  float den = 0.f;
  #pragma unroll
  for (int r = 0; r < 8; ++r) {
    float s = (v[r] - mean) * ia - smax;
    v[r] = s;
    den += __expf(s);
  }
  #pragma unroll
  for (int o = 32; o > 0; o >>= 1) den += __shfl_down(den, o);
  if ((t & 63) == 0) sa[t >> 6] = den;
  __syncthreads();
  den = sa[0] + sa[1] + sa[2] + sa[3];
  float logden = __logf(den);
  float invden = 1.f / den;
  __syncthreads();

  float ent = 0.f;
  #pragma unroll
  for (int r = 0; r < 8; ++r) {
    float s = v[r];
    float pv = __expf(s) * invden;
    HTp[(long)e * NTOT + t + 256 * r] = pv;
    ent += pv * (s - logden);
  }
  #pragma unroll
  for (int o = 32; o > 0; o >>= 1) ent += __shfl_down(ent, o);
  if ((t & 63) == 0) sa[t >> 6] = ent;
  __syncthreads();
  if (t == 0) Ecol[e] = sa[0] + sa[1] + sa[2] + sa[3];
}

// ---------------------------------------------------------------- jsd + xz (fused launch)
// bid < 512: Xzs partial H^T x (longer jobs dispatched FIRST for shorter tail)
// bid >= 512: pairwise-JSD log part (36 tile-pairs x 16 n-splits)
__global__ __launch_bounds__(256) void jx_k(const float* __restrict__ HTp,
                                            const float* __restrict__ xt, const float* __restrict__ xn,
                                            float* __restrict__ g, float* __restrict__ Xzs) {
  __shared__ union {
    struct { float Ti[JT][JNC + 2], Tj[JT][JNC + 2], red[JT][JT + 1]; } j;   // 17.7 KB
    struct { float As[32][33], Bs[32][36]; } x;                              // 8.8 KB
  } sm;
  int bid = blockIdx.x;
  int tid = threadIdx.x;

  if (bid >= 512) {
    // ---- jsd: single JNC-wide chunk per job
    int jj = bid - 512;
    int ny = jj / 36, b = jj - ny * 36;
    int bi = 0, rem = b;
    while (rem >= 8 - bi) { rem -= 8 - bi; ++bi; }
    int bj = bi + rem;                      // bi <= bj
    int n0 = ny * (NTOT / JNSPLIT);         // == ny * JNC
    int ti = tid >> 4, tj = tid & 15;
    bool active = (bi != bj) || (ti < tj);
    int lc = tid >> 4, ln = (tid & 15) * 8;
    const float* si = HTp + (long)(bi * JT + lc) * NTOT + n0 + ln;
    const float* sj = HTp + (long)(bj * JT + lc) * NTOT + n0 + ln;
    #pragma unroll
    for (int r = 0; r < 8; ++r) sm.j.Ti[lc][ln + r] = si[r];
    #pragma unroll
    for (int r = 0; r < 8; ++r) sm.j.Tj[lc][ln + r] = sj[r];
    __syncthreads();
    float acc = 0.f;
    if (active) {
      #pragma unroll 4
      for (int n = 0; n < JNC; ++n) {
        float s = sm.j.Ti[ti][n] + sm.j.Tj[tj][n];
        acc += s * __logf(fmaxf(0.5f * s, 1e-38f));
      }
    }
    sm.j.red[ti][tj] = active ? acc : 0.f;
    __syncthreads();
    if (tid < JT) {
      float s = 0.f;
      #pragma unroll
      for (int q = 0; q < JT; ++q) s += sm.j.red[tid][q];
      atomicAdd(&g[bi * JT + tid], -s);
    } else if (tid < 2 * JT) {
      int c2 = tid - JT;
      float s = 0.f;
      #pragma unroll
      for (int i = 0; i < JT; ++i) s += sm.j.red[i][c2];
      atomicAdd(&g[bj * JT + c2], -s);
    }
  } else {
    // ---- xz: Xzs[bt][split][e][d] = partial sum_n Hsoft[n,e] x[n][d]
    int id = bid;
    int bt = id >> 8;
    int split = (id >> 4) & 15;
    int t16 = id & 15;
    const float* x = bt ? xn : xt;
    float* C = Xzs + ((long)bt * ZSPLIT + split) * 16384;
    int e0 = (t16 & 3) * 32, d0 = (t16 >> 2) * 32;
    int n0 = split * (NTOT / ZSPLIT);
    int col = tid & 31, row = tid >> 5;
    int lr = tid >> 3, lc4 = (tid & 7) * 4;
    int tx = tid & 15, ty = tid >> 4;
    float a00 = 0.f, a01 = 0.f, a10 = 0.f, a11 = 0.f;
    float pa[4]; float4 pb;
    #pragma unroll
    for (int r = 0; r < 4; ++r) pa[r] = HTp[(long)(e0 + row + r * 8) * NTOT + n0 + col];
    pb = *(const float4*)(x + (long)(n0 + lr) * DIM + d0 + lc4);
    for (int nb = 0; nb < NTOT / ZSPLIT; nb += 32) {
      #pragma unroll
      for (int r = 0; r < 4; ++r) sm.x.As[col][row + r * 8] = pa[r];
      *(float4*)&sm.x.Bs[lr][lc4] = pb;
      __syncthreads();
      if (nb + 32 < NTOT / ZSPLIT) {
        #pragma unroll
        for (int r = 0; r < 4; ++r)
          pa[r] = HTp[(long)(e0 + row + r * 8) * NTOT + n0 + nb + 32 + col];
        pb = *(const float4*)(x + (long)(n0 + nb + 32 + lr) * DIM + d0 + lc4);
      }
      #pragma unroll
      for (int nn = 0; nn < 32; ++nn) {
        float e0v = sm.x.As[nn][2*ty], e1v = sm.x.As[nn][2*ty+1];
        float d0v = sm.x.Bs[nn][2*tx], d1v = sm.x.Bs[nn][2*tx+1];
        a00 += e0v * d0v; a01 += e0v * d1v;
        a10 += e1v * d0v; a11 += e1v * d1v;
      }
      __syncthreads();
    }
    int e = e0 + 2 * ty, d = d0 + 2 * tx;
    C[e * DIM + d]           = a00;
    C[e * DIM + d + 1]       = a01;
    C[(e + 1) * DIM + d]     = a10;
    C[(e + 1) * DIM + d + 1] = a11;
  }
}

// Zw[bt][e][d] = w[e] * sum_k (sum_s Xzs[bt][s][e][k]) * theta[k][d]
// 256 threads: halves split the 16-slab sum (8 each) and the theta dot
// (64 k each), combining via LDS. w butterfly per-wave (proven round 2).
// grid (128, 2), block 256.
__global__ __launch_bounds__(256) void zs_k(const float* __restrict__ Xzs, const float* __restrict__ thT,
                                            const float* __restrict__ thN, const float* __restrict__ g,
                                            const float* __restrict__ Ecol, float* __restrict__ Zw) {
  int e = blockIdx.x, bt = blockIdx.y;
  int d = threadIdx.x & 127, hf = threadIdx.x >> 7;
  float we;
  {
    int l = threadIdx.x & 63;
    float gA = g[l], gB = g[l + 64];
    float eA = Ecol[l], eB = Ecol[l + 64];
    float S = eA + eB;
    #pragma unroll
    for (int o = 32; o > 0; o >>= 1) S += __shfl_xor(S, o);
    float jA = (gA + 126.f * eA + S) * (1.f / 256.f);
    float jB = (gB + 126.f * eB + S) * (1.f / 256.f);
    float sn = jA + jB;
    #pragma unroll
    for (int o = 32; o > 0; o >>= 1) sn += __shfl_xor(sn, o);
    float mean = sn * (1.f / 128.f);
    float dA = jA - mean, dB = jB - mean;
    float q = dA * dA + dB * dB;
    #pragma unroll
    for (int o = 32; o > 0; o >>= 1) q += __shfl_xor(q, o);
    float inv = 1.f / (sqrtf(q * (1.f / 127.f)) + 1e-6f);
    float nA = dA * inv, nB = dB * inv;
    float mx = fmaxf(nA, nB);
    #pragma unroll
    for (int o = 32; o > 0; o >>= 1) mx = fmaxf(mx, __shfl_xor(mx, o));
    float xA = __expf(nA - mx), xB = __expf(nB - mx);
    float den = xA + xB;
    #pragma unroll
    for (int o = 32; o > 0; o >>= 1) den += __shfl_xor(den, o);
    float sel = (e < 64) ? nA : nB;
    float ne = __shfl(sel, e & 63);
    we = __expf(ne - mx) / den;
  }
  __shared__ float sx[2][DIM];
  __shared__ float s[DIM];
  __shared__ float sp[2][DIM];
  const float* src = Xzs + (long)bt * ZSPLIT * 16384 + e * DIM + d;
  float xv = 0.f;
  #pragma unroll
  for (int i = 0; i < 8; ++i) xv += src[(hf * 8 + i) * 16384];
  sx[hf][d] = xv;
  __syncthreads();
  if (hf == 0) s[d] = sx[0][d] + sx[1][d];
  __syncthreads();
  const float* th = bt ? thN : thT;
  float acc = 0.f;
  int k0 = hf * 64;
  #pragma unroll 8
  for (int k = k0; k < k0 + 64; ++k) acc += s[k] * th[(long)k * DIM + d];
  sp[hf][d] = acc;
  __syncthreads();
  if (hf == 0) Zw[bt * 16384 + e * DIM + d] = (sp[0][d] + sp[1][d]) * we;
}

// out[n][d] = x[n][d] + elu( sum_e Hsoft[n,e] Zw[e][d] )  (H read from HTp)
// grid (4, 64, 2), block 256. Register double-buffered staging.
__global__ __launch_bounds__(256) void uk_t(const float* __restrict__ HTp, const float* __restrict__ Zw,
                                            const float* __restrict__ xt, const float* __restrict__ xn,
                                            float* __restrict__ out) {
  int bt = blockIdx.z;
  const float* x = bt ? xn : xt;
  const float* B = Zw + bt * 16384;
  float* o = out + (long)bt * NTOT * DIM;
  int d0 = blockIdx.x * 32, n0 = blockIdx.y * 32;
  __shared__ float As[32][33], Bs[32][36];   // As[n][e], Bs[e][d]
  int tid = threadIdx.x, col = tid & 31, row = tid >> 5;
  int lr = tid >> 3, lc4 = (tid & 7) * 4;
  int tx = tid & 15, ty = tid >> 4;
  float a00 = 0.f, a01 = 0.f, a10 = 0.f, a11 = 0.f;
  float pa[4]; float4 pb;
  #pragma unroll
  for (int r = 0; r < 4; ++r) pa[r] = HTp[(long)(row + r * 8) * NTOT + n0 + col];
  pb = *(const float4*)(B + (long)lr * DIM + d0 + lc4);
  for (int eb = 0; eb < DIM; eb += 32) {
    #pragma unroll
    for (int r = 0; r < 4; ++r) As[col][row + r * 8] = pa[r];
    *(float4*)&Bs[lr][lc4] = pb;
    __syncthreads();
    if (eb + 32 < DIM) {
      #pragma unroll
      for (int r = 0; r < 4; ++r)
        pa[r] = HTp[(long)(eb + 32 + row + r * 8) * NTOT + n0 + col];
      pb = *(const float4*)(B + (long)(eb + 32 + lr) * DIM + d0 + lc4);
    }
    #pragma unroll
    for (int ee = 0; ee < 32; ++ee) {
      float x0 = As[2*ty][ee], x1 = As[2*ty+1][ee];
      float b0 = Bs[ee][2*tx], b1 = Bs[ee][2*tx+1];
      a00 += x0 * b0; a01 += x0 * b1;
      a10 += x1 * b0; a11 += x1 * b1;
    }
    __syncthreads();
  }
  int n = n0 + 2 * ty, d = d0 + 2 * tx;
  long i0 = (long)n * DIM + d, i1 = i0 + DIM;
  float e00 = a00 > 0.f ? a00 : expm1f(a00);
  float e01 = a01 > 0.f ? a01 : expm1f(a01);
  float e10 = a10 > 0.f ? a10 : expm1f(a10);
  float e11 = a11 > 0.f ? a11 : expm1f(a11);
  o[i0]     = x[i0]     + e00;
  o[i0 + 1] = x[i0 + 1] + e01;
  o[i1]     = x[i1]     + e10;
  o[i1 + 1] = x[i1 + 1] + e11;
}

// ---------------------------------------------------------------- launcher
extern "C" void kernel_launch(void* const* d_in, const int* in_sizes, int n_in,
                              void* d_out, int out_size, void* d_ws, size_t ws_size,
                              hipStream_t stream) {
  const float* xt = (const float*)d_in[0];   // x_time (f32)
  const float* xn = (const float*)d_in[1];   // x_news
  const float *W1[4], *b1[4], *W2[4], *b2[4];
  for (int k = 0; k < 4; ++k) {           // it, inw, t2n, n2t
    W1[k] = (const float*)d_in[2 + 4*k];
    b1[k] = (const float*)d_in[3 + 4*k];
    W2[k] = (const float*)d_in[4 + 4*k];
    b2[k] = (const float*)d_in[5 + 4*k];
  }
  const float* fW1 = (const float*)d_in[18];
  const float* fb1 = (const float*)d_in[19];
  const float* fW2 = (const float*)d_in[20];
  const float* fb2 = (const float*)d_in[21];
  const float* thT = (const float*)d_in[22];
  const float* thN = (const float*)d_in[23];

  // ws map (floats), peak 2163072 = 8.65 MB (no host-side zeroing needed)
  float* ws    = (float*)d_ws;
  float* Gacc  = ws;                         // [0,128)  zeroed by colsoft block 0
  float* Ecol  = ws + 128;                   // [128,256)
  float* Zw    = ws + 384;                   // [384,33152)
  float* Xzs   = ws + 33152;                 // 2*ZSPLIT*16384 = 524288 -> 557440
  float* Gs    = ws + 557440;                // 4*MSPLIT*16384 = 1048576 -> 1606016
  float* AB    = ws + 1606016;               // 32768 -> 1638784
  float* HrawT = ws + 1638784;               // 262144 -> 1900928 (transposed [e][n])
  float* HTp   = ws + 1900928;               // 262144 -> 2163072

  float* out = (float*)d_out;                // f32 output, [time | news]

  P4 Xs  = {{xt, xn, xn, xt}};
  P4 W1s = {{W1[0], W1[1], W1[2], W1[3]}};
  P4 B1s = {{b1[0], b1[1], b1[2], b1[3]}};
  P4 W2s = {{W2[0], W2[1], W2[2], W2[3]}};
  P4 B2s = {{b2[0], b2[1], b2[2], b2[3]}};

  gk_mlp1t<<<dim3(16, MSPLIT, 4), 256, 0, stream>>>(Xs, W1s, Gs);
  gk_mab  <<<128, 512, 0, stream>>>(Gs, B1s, W2s, B2s, fW1, AB);
  gk_h12t <<<256, 512, 0, stream>>>(xt, xn, AB, fb1, fW2, fb2, HrawT);

  colsoft_k<<<DIM, 256, 0, stream>>>(HrawT, HTp, Ecol, Gacc);

  jx_k<<<512 + 576, 256, 0, stream>>>(HTp, xt, xn, Gacc, Xzs);

  zs_k<<<dim3(128, 2), 256, 0, stream>>>(Xzs, thT, thN, Gacc, Ecol, Zw);
  uk_t<<<dim3(4, 64, 2), 256, 0, stream>>>(HTp, Zw, xt, xn, out);

  (void)in_sizes; (void)n_in; (void)out_size; (void)ws_size;
}